// Round 1
// baseline (651.558 us; speedup 1.0000x reference)
//
#include <hip/hip_runtime.h>
#include <stdint.h>

typedef __attribute__((ext_vector_type(8))) short bf16x8;
typedef __attribute__((ext_vector_type(4))) float f32x4;

static __device__ __forceinline__ unsigned short f2b(float f) {
    unsigned int u = __float_as_uint(f);
    unsigned int r = u + 0x7fffu + ((u >> 16) & 1u);   // RNE
    return (unsigned short)(r >> 16);
}

// ---------------- CSR build ----------------

__global__ void count_deg(const int* __restrict__ dst, int E, int* __restrict__ counts) {
    int e = blockIdx.x * 256 + threadIdx.x;
    if (e < E) atomicAdd(&counts[dst[e]], 1);
}

__global__ void scan_k(const int* __restrict__ counts, int N,
                       int* __restrict__ rowstart, int* __restrict__ cursor,
                       float* __restrict__ dinv) {
    __shared__ int wsum[16];
    __shared__ int carry_s;
    int tid = threadIdx.x;
    int wave = tid >> 6, lane = tid & 63;
    if (tid == 0) carry_s = 0;
    __syncthreads();
    for (int base = 0; base < N; base += 1024) {
        int i = base + tid;
        int c = (i < N) ? counts[i] : 0;
        int x = c;
        #pragma unroll
        for (int off = 1; off < 64; off <<= 1) {
            int v = __shfl_up(x, off);
            if (lane >= off) x += v;
        }
        if (lane == 63) wsum[wave] = x;
        __syncthreads();
        int pre = 0, tot = 0;
        #pragma unroll
        for (int w = 0; w < 16; ++w) {
            int s = wsum[w];
            tot += s;
            if (w < wave) pre += s;
        }
        int excl = carry_s + pre + x - c;
        if (i < N) {
            rowstart[i] = excl;
            cursor[i] = excl;
            dinv[i] = rsqrtf((float)(c + 1));
        }
        __syncthreads();
        if (tid == 0) carry_s += tot;
    }
    __syncthreads();
    if (tid == 0) rowstart[N] = carry_s;
}

__global__ void fill_csr(const int* __restrict__ src, const int* __restrict__ dst, int E,
                         int* __restrict__ cursor, int* __restrict__ csr_src) {
    int e = blockIdx.x * 256 + threadIdx.x;
    if (e < E) {
        int p = atomicAdd(&cursor[dst[e]], 1);
        csr_src[p] = src[e];
    }
}

// ---------------- fp32 node GEMM: t = in @ W   [N,128]x[128,128] ----------------

__global__ __launch_bounds__(256) void node_gemm(const float* __restrict__ in,
                                                 const float* __restrict__ W,
                                                 float* __restrict__ out, int N) {
    __shared__ __align__(16) float rl[8][128];
    int tid = threadIdx.x;
    int rowbase = blockIdx.x * 8;
    {
        int r = tid >> 5;
        int k0 = (tid & 31) * 4;
        int row = rowbase + r;
        if (row >= N) row = N - 1;
        *(float4*)&rl[r][k0] = *(const float4*)(in + (size_t)row * 128 + k0);
    }
    __syncthreads();
    int f = tid & 127;
    int rh = tid >> 7;            // 0..1, owns rows rh*4 .. rh*4+3
    float a0 = 0.f, a1 = 0.f, a2 = 0.f, a3 = 0.f;
    for (int k = 0; k < 128; ++k) {
        float w = W[k * 128 + f];
        a0 = fmaf(rl[rh * 4 + 0][k], w, a0);
        a1 = fmaf(rl[rh * 4 + 1][k], w, a1);
        a2 = fmaf(rl[rh * 4 + 2][k], w, a2);
        a3 = fmaf(rl[rh * 4 + 3][k], w, a3);
    }
    int r0 = rowbase + rh * 4;
    if (r0 + 0 < N) out[(size_t)(r0 + 0) * 128 + f] = a0;
    if (r0 + 1 < N) out[(size_t)(r0 + 1) * 128 + f] = a1;
    if (r0 + 2 < N) out[(size_t)(r0 + 2) * 128 + f] = a2;
    if (r0 + 3 < N) out[(size_t)(r0 + 3) * 128 + f] = a3;
}

// ---------------- GCN aggregation ----------------

template <int RELU, int BF16OUT>
__global__ void aggregate(const float* __restrict__ t, const int* __restrict__ rowstart,
                          const int* __restrict__ csr_src, const float* __restrict__ dinv,
                          const float* __restrict__ bias, float* __restrict__ hout,
                          unsigned short* __restrict__ hb_out) {
    int i = blockIdx.x;
    int f = threadIdx.x;
    float di = dinv[i];
    float acc = bias[f] + di * di * t[(size_t)i * 128 + f];
    int rs = rowstart[i], re = rowstart[i + 1];
    for (int e = rs; e < re; ++e) {
        int s = csr_src[e];
        acc = fmaf(dinv[s] * di, t[(size_t)s * 128 + f], acc);
    }
    if (RELU) acc = fmaxf(acc, 0.f);
    if (BF16OUT) hb_out[(size_t)i * 128 + f] = f2b(acc);
    else        hout[(size_t)i * 128 + f] = acc;
}

// ---------------- edge head: relu(ef@Wm1+bm1)@Wm2+bm2, ef=[h3[src],h3[dst]] ----------------
// Orientation: features = M (A operand, weights in registers), edges = N (B operand).
// C[f][e]; MFMA 16x16x32 bf16. 64-edge tiles, 4 waves, wave w owns f in [w*32, w*32+32).

__global__ __launch_bounds__(256, 2) void edge_head(
    const unsigned short* __restrict__ h3b, const int* __restrict__ src,
    const int* __restrict__ dst, const float* __restrict__ Wm1,
    const float* __restrict__ bm1, const float* __restrict__ Wm2,
    const float* __restrict__ bm2, float* __restrict__ out, int E, int ntiles) {
    __shared__ __align__(16) unsigned short ef[64][264];   // [edge][k 0..255], pad 8
    __shared__ __align__(16) unsigned short zl[64][136];   // [edge][f1], pad 8
    float (*outl)[132] = (float (*)[132])(void*)ef;        // reuse ef region for fp32 out

    int tid = threadIdx.x;
    int wid = tid >> 6;
    int lane = tid & 63;
    int lg = lane >> 4;       // k-group 0..3
    int l15 = lane & 15;      // row/col within tile
    int lane16 = tid & 15;

    // ---- one-time: weight fragments into registers ----
    bf16x8 a1[2][8];   // Wm1^T: A1[m=f1][k],  f1 = wid*32 + mt*16 + l15
    bf16x8 a2[2][4];   // Wm2^T: A2[m=f2][k=f1]
    float b1v[2][4], b2v[2][4];
    #pragma unroll
    for (int mt = 0; mt < 2; ++mt) {
        int m = wid * 32 + mt * 16 + l15;
        #pragma unroll
        for (int kk = 0; kk < 8; ++kk) {
            bf16x8 a;
            #pragma unroll
            for (int ee = 0; ee < 8; ++ee)
                a[ee] = (short)f2b(Wm1[(kk * 32 + lg * 8 + ee) * 128 + m]);
            a1[mt][kk] = a;
        }
        #pragma unroll
        for (int kk = 0; kk < 4; ++kk) {
            bf16x8 a;
            #pragma unroll
            for (int ee = 0; ee < 8; ++ee)
                a[ee] = (short)f2b(Wm2[(kk * 32 + lg * 8 + ee) * 128 + m]);
            a2[mt][kk] = a;
        }
        #pragma unroll
        for (int r = 0; r < 4; ++r) {
            b1v[mt][r] = bm1[wid * 32 + mt * 16 + lg * 4 + r];
            b2v[mt][r] = bm2[wid * 32 + mt * 16 + lg * 4 + r];
        }
    }

    for (int tile = blockIdx.x; tile < ntiles; tile += gridDim.x) {
        __syncthreads();   // previous iteration's out-copy finished with ef region
        // ---- stage ef tile: 64 edges x 256 bf16 ----
        int hrb = tid >> 4;                // 0..15
        #pragma unroll
        for (int p = 0; p < 8; ++p) {
            int hr = p * 16 + hrb;         // 0..127 half-rows
            int eloc = hr >> 1, half = hr & 1;
            int eg = tile * 64 + eloc;
            if (eg >= E) eg = E - 1;
            int node = half ? dst[eg] : src[eg];
            uint4 v = *(const uint4*)(h3b + (size_t)node * 128 + lane16 * 8);
            *(uint4*)&ef[eloc][half * 128 + lane16 * 8] = v;
        }
        __syncthreads();

        // ---- GEMM1: C1[f1][e] = sum_k Wm1[k][f1] * ef[e][k] ----
        f32x4 c1[2][4];
        #pragma unroll
        for (int mt = 0; mt < 2; ++mt)
            #pragma unroll
            for (int nt = 0; nt < 4; ++nt) c1[mt][nt] = (f32x4){0.f, 0.f, 0.f, 0.f};
        #pragma unroll
        for (int kk = 0; kk < 8; ++kk) {
            #pragma unroll
            for (int nt = 0; nt < 4; ++nt) {
                bf16x8 b = *(const bf16x8*)&ef[nt * 16 + l15][kk * 32 + lg * 8];
                c1[0][nt] = __builtin_amdgcn_mfma_f32_16x16x32_bf16(a1[0][kk], b, c1[0][nt], 0, 0, 0);
                c1[1][nt] = __builtin_amdgcn_mfma_f32_16x16x32_bf16(a1[1][kk], b, c1[1][nt], 0, 0, 0);
            }
        }
        // z = relu(C1 + bm1) -> bf16 -> zl[e][f1]
        #pragma unroll
        for (int mt = 0; mt < 2; ++mt) {
            #pragma unroll
            for (int nt = 0; nt < 4; ++nt) {
                float z0 = fmaxf(c1[mt][nt][0] + b1v[mt][0], 0.f);
                float z1 = fmaxf(c1[mt][nt][1] + b1v[mt][1], 0.f);
                float z2 = fmaxf(c1[mt][nt][2] + b1v[mt][2], 0.f);
                float z3 = fmaxf(c1[mt][nt][3] + b1v[mt][3], 0.f);
                unsigned int u0 = (unsigned int)f2b(z0) | ((unsigned int)f2b(z1) << 16);
                unsigned int u1 = (unsigned int)f2b(z2) | ((unsigned int)f2b(z3) << 16);
                *(uint2*)&zl[nt * 16 + l15][wid * 32 + mt * 16 + lg * 4] = make_uint2(u0, u1);
            }
        }
        __syncthreads();

        // ---- GEMM2: C2[f2][e] = sum_f1 Wm2[f1][f2] * z[e][f1] ----
        f32x4 c2[2][4];
        #pragma unroll
        for (int mt = 0; mt < 2; ++mt)
            #pragma unroll
            for (int nt = 0; nt < 4; ++nt) c2[mt][nt] = (f32x4){0.f, 0.f, 0.f, 0.f};
        #pragma unroll
        for (int kk = 0; kk < 4; ++kk) {
            #pragma unroll
            for (int nt = 0; nt < 4; ++nt) {
                bf16x8 b = *(const bf16x8*)&zl[nt * 16 + l15][kk * 32 + lg * 8];
                c2[0][nt] = __builtin_amdgcn_mfma_f32_16x16x32_bf16(a2[0][kk], b, c2[0][nt], 0, 0, 0);
                c2[1][nt] = __builtin_amdgcn_mfma_f32_16x16x32_bf16(a2[1][kk], b, c2[1][nt], 0, 0, 0);
            }
        }
        // out tile -> LDS (fp32), overwrites ef region (GEMM1 done for all waves)
        #pragma unroll
        for (int mt = 0; mt < 2; ++mt) {
            #pragma unroll
            for (int nt = 0; nt < 4; ++nt) {
                f32x4 o;
                #pragma unroll
                for (int r = 0; r < 4; ++r) o[r] = c2[mt][nt][r] + b2v[mt][r];
                *(f32x4*)&outl[nt * 16 + l15][wid * 32 + mt * 16 + lg * 4] = o;
            }
        }
        __syncthreads();
        // coalesced copy: 64 rows x 512B
        #pragma unroll
        for (int p = 0; p < 8; ++p) {
            int row = p * 8 + (tid >> 5);
            int chunk = (tid >> 4) & 1;
            int fo = chunk * 64 + lane16 * 4;
            int eg = tile * 64 + row;
            if (eg < E) {
                f32x4 v = *(const f32x4*)&outl[row][fo];
                *(f32x4*)(out + (size_t)eg * 128 + fo) = v;
            }
        }
    }
}

// ---------------- launch ----------------

extern "C" void kernel_launch(void* const* d_in, const int* in_sizes, int n_in,
                              void* d_out, int out_size, void* d_ws, size_t ws_size,
                              hipStream_t stream) {
    const float* x  = (const float*)d_in[0];
    const int*   ei = (const int*)d_in[1];
    const float* W1 = (const float*)d_in[2];
    const float* b1 = (const float*)d_in[3];
    const float* W2 = (const float*)d_in[4];
    const float* b2 = (const float*)d_in[5];
    const float* W3 = (const float*)d_in[6];
    const float* b3 = (const float*)d_in[7];
    const float* Wm1 = (const float*)d_in[8];
    const float* bm1 = (const float*)d_in[9];
    const float* Wm2 = (const float*)d_in[10];
    const float* bm2 = (const float*)d_in[11];
    float* out = (float*)d_out;

    const int N = in_sizes[0] / 128;
    const int E = in_sizes[1] / 2;
    const int* src = ei;
    const int* dstp = ei + E;

    // workspace bump allocator (256B aligned)
    uintptr_t base = (uintptr_t)d_ws;
    auto alloc = [&](size_t bytes) -> void* {
        uintptr_t p = base;
        base += (bytes + 255) & ~(uintptr_t)255;
        return (void*)p;
    };
    int*   counts   = (int*)alloc((size_t)(N + 1) * 4);
    int*   rowstart = (int*)alloc((size_t)(N + 1) * 4);
    int*   cursor   = (int*)alloc((size_t)N * 4);
    float* dinv     = (float*)alloc((size_t)N * 4);
    int*   csr      = (int*)alloc((size_t)E * 4);
    float* t        = (float*)alloc((size_t)N * 128 * 4);
    float* h        = (float*)alloc((size_t)N * 128 * 4);
    unsigned short* h3b = (unsigned short*)alloc((size_t)N * 128 * 2);
    (void)ws_size; (void)n_in; (void)out_size;

    hipMemsetAsync(counts, 0, (size_t)(N + 1) * 4, stream);

    int egrid = (E + 255) / 256;
    count_deg<<<egrid, 256, 0, stream>>>(dstp, E, counts);
    scan_k<<<1, 1024, 0, stream>>>(counts, N, rowstart, cursor, dinv);
    fill_csr<<<egrid, 256, 0, stream>>>(src, dstp, E, cursor, csr);

    int ggrid = (N + 7) / 8;
    // layer 1
    node_gemm<<<ggrid, 256, 0, stream>>>(x, W1, t, N);
    aggregate<1, 0><<<N, 128, 0, stream>>>(t, rowstart, csr, dinv, b1, h, nullptr);
    // layer 2
    node_gemm<<<ggrid, 256, 0, stream>>>(h, W2, t, N);
    aggregate<1, 0><<<N, 128, 0, stream>>>(t, rowstart, csr, dinv, b2, h, nullptr);
    // layer 3 -> bf16 h3
    node_gemm<<<ggrid, 256, 0, stream>>>(h, W3, t, N);
    aggregate<0, 1><<<N, 128, 0, stream>>>(t, rowstart, csr, dinv, b3, nullptr, h3b);

    int ntiles = (E + 63) / 64;
    int hgrid = ntiles < 1024 ? ntiles : 1024;
    edge_head<<<hgrid, 256, 0, stream>>>(h3b, src, dstp, Wm1, bm1, Wm2, bm2, out, E, ntiles);
}

// Round 2
// 595.773 us; speedup vs baseline: 1.0936x; 1.0936x over previous
//
#include <hip/hip_runtime.h>
#include <stdint.h>

typedef __attribute__((ext_vector_type(8))) short bf16x8;
typedef __attribute__((ext_vector_type(4))) float f32x4;

static __device__ __forceinline__ unsigned short f2b(float f) {
    unsigned int u = __float_as_uint(f);
    unsigned int r = u + 0x7fffu + ((u >> 16) & 1u);   // RNE
    return (unsigned short)(r >> 16);
}

// ---------------- CSR build ----------------

__global__ void count_deg(const int* __restrict__ dst, int E, int* __restrict__ counts) {
    int e = blockIdx.x * 256 + threadIdx.x;
    if (e < E) atomicAdd(&counts[dst[e]], 1);
}

// block-local exclusive scan of 1024 counts; writes per-block total to psum
__global__ void scan_s1(const int* __restrict__ counts, int N,
                        int* __restrict__ rowstart, float* __restrict__ dinv,
                        int* __restrict__ psum) {
    __shared__ int wsum[16];
    int tid = threadIdx.x, wave = tid >> 6, lane = tid & 63;
    int i = blockIdx.x * 1024 + tid;
    int c = (i < N) ? counts[i] : 0;
    int x = c;
    #pragma unroll
    for (int off = 1; off < 64; off <<= 1) {
        int v = __shfl_up(x, off);
        if (lane >= off) x += v;
    }
    if (lane == 63) wsum[wave] = x;
    __syncthreads();
    int pre = 0, tot = 0;
    #pragma unroll
    for (int w = 0; w < 16; ++w) {
        int s = wsum[w];
        tot += s;
        if (w < wave) pre += s;
    }
    if (i < N) {
        rowstart[i] = pre + x - c;           // block-local exclusive
        dinv[i] = rsqrtf((float)c + 1.0f);
    }
    if (tid == 0) psum[blockIdx.x] = tot;
}

// scan the block sums (nchunk <= 1024)
__global__ void scan_s2(int* __restrict__ psum, int nchunk,
                        int* __restrict__ rowstart, int N) {
    __shared__ int wsum[16];
    int tid = threadIdx.x, wave = tid >> 6, lane = tid & 63;
    int v = (tid < nchunk) ? psum[tid] : 0;
    int x = v;
    #pragma unroll
    for (int off = 1; off < 64; off <<= 1) {
        int s = __shfl_up(x, off);
        if (lane >= off) x += s;
    }
    if (lane == 63) wsum[wave] = x;
    __syncthreads();
    int pre = 0, tot = 0;
    #pragma unroll
    for (int w = 0; w < 16; ++w) {
        int s = wsum[w];
        tot += s;
        if (w < wave) pre += s;
    }
    if (tid < nchunk) psum[tid] = pre + x - v;   // exclusive block offsets
    if (tid == 0) rowstart[N] = tot;
}

__global__ void scan_s3(int* __restrict__ rowstart, const int* __restrict__ psum,
                        int N, int* __restrict__ cursor) {
    int i = blockIdx.x * 1024 + threadIdx.x;
    if (i < N) {
        int r = rowstart[i] + psum[blockIdx.x];
        rowstart[i] = r;
        cursor[i] = r;
    }
}

__global__ void fill_csr(const int* __restrict__ src, const int* __restrict__ dst, int E,
                         int* __restrict__ cursor, int* __restrict__ csr_src) {
    int e = blockIdx.x * 256 + threadIdx.x;
    if (e < E) {
        int p = atomicAdd(&cursor[dst[e]], 1);
        csr_src[p] = src[e];
    }
}

// ---------------- fp32 node GEMM: t = in @ W   [N,128]x[128,128] ----------------
// 64 rows/block in LDS; thread = 8 rows x 4 cols; 4-k unrolled float4 reads.

__global__ __launch_bounds__(256) void node_gemm(const float* __restrict__ in,
                                                 const float* __restrict__ W,
                                                 float* __restrict__ out, int N) {
    __shared__ __align__(16) float rl[64][128];
    int tid = threadIdx.x;
    int rowbase = blockIdx.x * 64;
    #pragma unroll
    for (int p = 0; p < 8; ++p) {
        int idx = p * 256 + tid;
        int r = idx >> 5, c4 = (idx & 31) * 4;
        int row = rowbase + r;
        if (row >= N) row = N - 1;
        *(float4*)&rl[r][c4] = *(const float4*)(in + (size_t)row * 128 + c4);
    }
    __syncthreads();
    int rg = tid >> 5, cg = tid & 31, f0 = cg * 4;
    f32x4 acc[8];
    #pragma unroll
    for (int i = 0; i < 8; ++i) acc[i] = (f32x4){0.f, 0.f, 0.f, 0.f};
    for (int k = 0; k < 128; k += 4) {
        f32x4 w0 = *(const f32x4*)&W[(k + 0) * 128 + f0];
        f32x4 w1 = *(const f32x4*)&W[(k + 1) * 128 + f0];
        f32x4 w2 = *(const f32x4*)&W[(k + 2) * 128 + f0];
        f32x4 w3 = *(const f32x4*)&W[(k + 3) * 128 + f0];
        #pragma unroll
        for (int i = 0; i < 8; ++i) {
            f32x4 r4 = *(const f32x4*)&rl[rg * 8 + i][k];
            acc[i] += r4[0] * w0;
            acc[i] += r4[1] * w1;
            acc[i] += r4[2] * w2;
            acc[i] += r4[3] * w3;
        }
    }
    #pragma unroll
    for (int i = 0; i < 8; ++i) {
        int row = rowbase + rg * 8 + i;
        if (row < N) *(f32x4*)(out + (size_t)row * 128 + f0) = acc[i];
    }
}

// ---------------- GCN aggregation: 32 threads/node, float4 ----------------

template <int RELU, int BF16OUT>
__global__ __launch_bounds__(256) void aggregate(
        const float* __restrict__ t, const int* __restrict__ rowstart,
        const int* __restrict__ csr_src, const float* __restrict__ dinv,
        const float* __restrict__ bias, float* __restrict__ hout,
        unsigned short* __restrict__ hb_out, int N) {
    int tid = threadIdx.x;
    int node = blockIdx.x * 8 + (tid >> 5);
    if (node >= N) return;
    int c = (tid & 31) * 4;
    float di = dinv[node];
    f32x4 tv = *(const f32x4*)(t + (size_t)node * 128 + c);
    f32x4 acc = *(const f32x4*)(bias + c) + (di * di) * tv;
    int rs = rowstart[node], re = rowstart[node + 1];
    int e = rs;
    for (; e + 1 < re; e += 2) {
        int s0 = csr_src[e], s1 = csr_src[e + 1];
        float n0 = dinv[s0] * di;
        float n1 = dinv[s1] * di;
        f32x4 t0 = *(const f32x4*)(t + (size_t)s0 * 128 + c);
        f32x4 t1 = *(const f32x4*)(t + (size_t)s1 * 128 + c);
        acc += n0 * t0;
        acc += n1 * t1;
    }
    if (e < re) {
        int s0 = csr_src[e];
        acc += (dinv[s0] * di) * *(const f32x4*)(t + (size_t)s0 * 128 + c);
    }
    if (RELU) {
        #pragma unroll
        for (int j = 0; j < 4; ++j) acc[j] = fmaxf(acc[j], 0.f);
    }
    if (BF16OUT) {
        unsigned int u0 = (unsigned int)f2b(acc[0]) | ((unsigned int)f2b(acc[1]) << 16);
        unsigned int u1 = (unsigned int)f2b(acc[2]) | ((unsigned int)f2b(acc[3]) << 16);
        *(uint2*)(hb_out + (size_t)node * 128 + c) = make_uint2(u0, u1);
    } else {
        *(f32x4*)(hout + (size_t)node * 128 + c) = acc;
    }
}

// ---------------- uv precompute: uv[i][0:128]=h3@Wm1_top, uv[i][128:256]=h3@Wm1_bot ----
// MFMA 16x16x32 bf16; 64 nodes/block; wave w owns output cols w*64..w*64+63.

__global__ __launch_bounds__(256) void uv_gemm(const unsigned short* __restrict__ h3b,
                                               const float* __restrict__ Wm1,
                                               float* __restrict__ uv, int N) {
    __shared__ __align__(16) unsigned short hl[64][136];
    int tid = threadIdx.x;
    int wid = tid >> 6, lane = tid & 63;
    int lg = lane >> 4, l15 = lane & 15;
    int tilebase = blockIdx.x * 64;

    // A fragments: A[m=jc][k] = Wm1[k + 128*(jc>=128)][jc&127]
    bf16x8 a[4][4];
    #pragma unroll
    for (int mt = 0; mt < 4; ++mt) {
        int jc = wid * 64 + mt * 16 + l15;
        int koff = (jc >> 7) * 128;
        int col = jc & 127;
        #pragma unroll
        for (int kk = 0; kk < 4; ++kk) {
            bf16x8 af;
            #pragma unroll
            for (int ee = 0; ee < 8; ++ee)
                af[ee] = (short)f2b(Wm1[(size_t)(koff + kk * 32 + lg * 8 + ee) * 128 + col]);
            a[mt][kk] = af;
        }
    }

    // stage 64 h3 rows
    #pragma unroll
    for (int p = 0; p < 4; ++p) {
        int idx = p * 256 + tid;
        int r = idx >> 4, ci = idx & 15;
        int row = tilebase + r;
        if (row >= N) row = N - 1;
        uint4 v = *(const uint4*)(h3b + (size_t)row * 128 + ci * 8);
        *(uint4*)&hl[r][ci * 8] = v;
    }
    __syncthreads();

    f32x4 acc[4][4];
    #pragma unroll
    for (int mt = 0; mt < 4; ++mt)
        #pragma unroll
        for (int nt = 0; nt < 4; ++nt) acc[mt][nt] = (f32x4){0.f, 0.f, 0.f, 0.f};
    #pragma unroll
    for (int kk = 0; kk < 4; ++kk) {
        #pragma unroll
        for (int nt = 0; nt < 4; ++nt) {
            bf16x8 b = *(const bf16x8*)&hl[nt * 16 + l15][kk * 32 + lg * 8];
            #pragma unroll
            for (int mt = 0; mt < 4; ++mt)
                acc[mt][nt] = __builtin_amdgcn_mfma_f32_16x16x32_bf16(a[mt][kk], b, acc[mt][nt], 0, 0, 0);
        }
    }
    #pragma unroll
    for (int mt = 0; mt < 4; ++mt) {
        int jc = wid * 64 + mt * 16 + lg * 4;
        #pragma unroll
        for (int nt = 0; nt < 4; ++nt) {
            int node = tilebase + nt * 16 + l15;
            if (node < N) *(f32x4*)(uv + (size_t)node * 256 + jc) = acc[mt][nt];
        }
    }
}

// ---------------- edge head: z = relu(u[src]+v[dst]+bm1); out = z@Wm2+bm2 ----------------

__global__ __launch_bounds__(256, 3) void edge_head2(
        const float* __restrict__ uv, const int* __restrict__ src,
        const int* __restrict__ dst, const float* __restrict__ bm1,
        const float* __restrict__ Wm2, const float* __restrict__ bm2,
        float* __restrict__ out, int E, int ntiles) {
    __shared__ __align__(16) unsigned short zl[64][136];
    int tid = threadIdx.x;
    int wid = tid >> 6, lane = tid & 63;
    int lg = lane >> 4, l15 = lane & 15;
    int es = tid >> 4;        // edge slot within 16-edge pass
    int ci = tid & 15;
    int c0 = ci * 8;

    // Wm2^T fragments + biases
    bf16x8 a2[2][4];
    float b2v[2][4];
    #pragma unroll
    for (int mt = 0; mt < 2; ++mt) {
        int m = wid * 32 + mt * 16 + l15;
        #pragma unroll
        for (int kk = 0; kk < 4; ++kk) {
            bf16x8 af;
            #pragma unroll
            for (int ee = 0; ee < 8; ++ee)
                af[ee] = (short)f2b(Wm2[(size_t)(kk * 32 + lg * 8 + ee) * 128 + m]);
            a2[mt][kk] = af;
        }
        #pragma unroll
        for (int r = 0; r < 4; ++r)
            b2v[mt][r] = bm2[wid * 32 + mt * 16 + lg * 4 + r];
    }
    float bm1v[8];
    #pragma unroll
    for (int j = 0; j < 8; ++j) bm1v[j] = bm1[c0 + j];

    for (int tile = blockIdx.x; tile < ntiles; tile += gridDim.x) {
        __syncthreads();   // all waves done reading zl from previous tile
        // ---- stage z: 4 passes x 16 edges ----
        #pragma unroll
        for (int p = 0; p < 4; ++p) {
            int eg = tile * 64 + p * 16 + es;
            if (eg >= E) eg = E - 1;
            int s = src[eg], d = dst[eg];
            const float* up = uv + (size_t)s * 256 + c0;
            const float* vp = uv + (size_t)d * 256 + 128 + c0;
            f32x4 u0 = *(const f32x4*)up;
            f32x4 u1 = *(const f32x4*)(up + 4);
            f32x4 v0 = *(const f32x4*)vp;
            f32x4 v1 = *(const f32x4*)(vp + 4);
            unsigned int w[4];
            #pragma unroll
            for (int j = 0; j < 4; ++j) {
                float z0 = fmaxf(u0[j] + v0[j] + bm1v[j], 0.f);
                (void)z0;
            }
            {
                float z0 = fmaxf(u0[0] + v0[0] + bm1v[0], 0.f);
                float z1 = fmaxf(u0[1] + v0[1] + bm1v[1], 0.f);
                float z2 = fmaxf(u0[2] + v0[2] + bm1v[2], 0.f);
                float z3 = fmaxf(u0[3] + v0[3] + bm1v[3], 0.f);
                float z4 = fmaxf(u1[0] + v1[0] + bm1v[4], 0.f);
                float z5 = fmaxf(u1[1] + v1[1] + bm1v[5], 0.f);
                float z6 = fmaxf(u1[2] + v1[2] + bm1v[6], 0.f);
                float z7 = fmaxf(u1[3] + v1[3] + bm1v[7], 0.f);
                w[0] = (unsigned int)f2b(z0) | ((unsigned int)f2b(z1) << 16);
                w[1] = (unsigned int)f2b(z2) | ((unsigned int)f2b(z3) << 16);
                w[2] = (unsigned int)f2b(z4) | ((unsigned int)f2b(z5) << 16);
                w[3] = (unsigned int)f2b(z6) | ((unsigned int)f2b(z7) << 16);
            }
            *(uint4*)&zl[p * 16 + es][c0] = make_uint4(w[0], w[1], w[2], w[3]);
        }
        __syncthreads();

        // ---- GEMM2: C[f2][e] = sum_f1 Wm2[f1][f2] * z[e][f1] ----
        f32x4 c2[2][4];
        #pragma unroll
        for (int mt = 0; mt < 2; ++mt)
            #pragma unroll
            for (int nt = 0; nt < 4; ++nt) c2[mt][nt] = (f32x4){0.f, 0.f, 0.f, 0.f};
        #pragma unroll
        for (int kk = 0; kk < 4; ++kk) {
            #pragma unroll
            for (int nt = 0; nt < 4; ++nt) {
                bf16x8 b = *(const bf16x8*)&zl[nt * 16 + l15][kk * 32 + lg * 8];
                c2[0][nt] = __builtin_amdgcn_mfma_f32_16x16x32_bf16(a2[0][kk], b, c2[0][nt], 0, 0, 0);
                c2[1][nt] = __builtin_amdgcn_mfma_f32_16x16x32_bf16(a2[1][kk], b, c2[1][nt], 0, 0, 0);
            }
        }
        // ---- bias + direct store (64B-contiguous chunks per lg-quad) ----
        #pragma unroll
        for (int mt = 0; mt < 2; ++mt) {
            #pragma unroll
            for (int nt = 0; nt < 4; ++nt) {
                int eg = tile * 64 + nt * 16 + l15;
                if (eg < E) {
                    f32x4 o;
                    #pragma unroll
                    for (int r = 0; r < 4; ++r) o[r] = c2[mt][nt][r] + b2v[mt][r];
                    *(f32x4*)(out + (size_t)eg * 128 + wid * 32 + mt * 16 + lg * 4) = o;
                }
            }
        }
    }
}

// ---------------- launch ----------------

extern "C" void kernel_launch(void* const* d_in, const int* in_sizes, int n_in,
                              void* d_out, int out_size, void* d_ws, size_t ws_size,
                              hipStream_t stream) {
    const float* x  = (const float*)d_in[0];
    const int*   ei = (const int*)d_in[1];
    const float* W1 = (const float*)d_in[2];
    const float* b1 = (const float*)d_in[3];
    const float* W2 = (const float*)d_in[4];
    const float* b2 = (const float*)d_in[5];
    const float* W3 = (const float*)d_in[6];
    const float* b3 = (const float*)d_in[7];
    const float* Wm1 = (const float*)d_in[8];
    const float* bm1 = (const float*)d_in[9];
    const float* Wm2 = (const float*)d_in[10];
    const float* bm2 = (const float*)d_in[11];
    float* out = (float*)d_out;

    const int N = in_sizes[0] / 128;
    const int E = in_sizes[1] / 2;
    const int* src = ei;
    const int* dstp = ei + E;

    uintptr_t base = (uintptr_t)d_ws;
    auto alloc = [&](size_t bytes) -> void* {
        uintptr_t p = base;
        base += (bytes + 255) & ~(uintptr_t)255;
        return (void*)p;
    };
    int*   counts   = (int*)alloc((size_t)(N + 1) * 4);
    int*   rowstart = (int*)alloc((size_t)(N + 1) * 4);
    int*   cursor   = (int*)alloc((size_t)N * 4);
    float* dinv     = (float*)alloc((size_t)N * 4);
    int*   psum     = (int*)alloc(4096);
    int*   csr      = (int*)alloc((size_t)E * 4);
    float* t        = (float*)alloc((size_t)N * 128 * 4);
    float* h        = (float*)alloc((size_t)N * 128 * 4);
    unsigned short* h3b = (unsigned short*)alloc((size_t)N * 128 * 2);
    float* uvbuf    = t;   // overlays t+h (both dead after layer-3 aggregate)
    (void)ws_size; (void)n_in; (void)out_size;

    hipMemsetAsync(counts, 0, (size_t)(N + 1) * 4, stream);

    int egrid = (E + 255) / 256;
    int nchunk = (N + 1023) / 1024;
    count_deg<<<egrid, 256, 0, stream>>>(dstp, E, counts);
    scan_s1<<<nchunk, 1024, 0, stream>>>(counts, N, rowstart, dinv, psum);
    scan_s2<<<1, 1024, 0, stream>>>(psum, nchunk, rowstart, N);
    scan_s3<<<nchunk, 1024, 0, stream>>>(rowstart, psum, N, cursor);
    fill_csr<<<egrid, 256, 0, stream>>>(src, dstp, E, cursor, csr);

    int ggrid = (N + 63) / 64;
    int agrid = (N + 7) / 8;
    node_gemm<<<ggrid, 256, 0, stream>>>(x, W1, t, N);
    aggregate<1, 0><<<agrid, 256, 0, stream>>>(t, rowstart, csr, dinv, b1, h, nullptr, N);
    node_gemm<<<ggrid, 256, 0, stream>>>(h, W2, t, N);
    aggregate<1, 0><<<agrid, 256, 0, stream>>>(t, rowstart, csr, dinv, b2, h, nullptr, N);
    node_gemm<<<ggrid, 256, 0, stream>>>(h, W3, t, N);
    aggregate<0, 1><<<agrid, 256, 0, stream>>>(t, rowstart, csr, dinv, b3, nullptr, h3b, N);

    uv_gemm<<<ggrid, 256, 0, stream>>>(h3b, Wm1, uvbuf, N);

    int ntiles = (E + 63) / 64;
    int hgrid = ntiles < 1024 ? ntiles : 1024;
    edge_head2<<<hgrid, 256, 0, stream>>>(uvbuf, src, dstp, bm1, Wm2, bm2, out, E, ntiles);
}

// Round 3
// 501.831 us; speedup vs baseline: 1.2984x; 1.1872x over previous
//
#include <hip/hip_runtime.h>
#include <stdint.h>

typedef __attribute__((ext_vector_type(8))) short bf16x8;
typedef __attribute__((ext_vector_type(4))) float f32x4;

static __device__ __forceinline__ unsigned short f2b(float f) {
    unsigned int u = __float_as_uint(f);
    unsigned int r = u + 0x7fffu + ((u >> 16) & 1u);   // RNE
    return (unsigned short)(r >> 16);
}
static __device__ __forceinline__ float b2f(unsigned short u) {
    return __uint_as_float((unsigned int)u << 16);
}
static __device__ __forceinline__ f32x4 b2f4(ushort4 u) {
    f32x4 r;
    r[0] = b2f(u.x); r[1] = b2f(u.y); r[2] = b2f(u.z); r[3] = b2f(u.w);
    return r;
}

// ---------------- CSR build ----------------

__global__ void count_deg(const int* __restrict__ dst, int E, int* __restrict__ counts) {
    int e = blockIdx.x * 256 + threadIdx.x;
    if (e < E) atomicAdd(&counts[dst[e]], 1);
}

__global__ void scan_s1(const int* __restrict__ counts, int N,
                        int* __restrict__ rowstart, float* __restrict__ dinv,
                        int* __restrict__ psum) {
    __shared__ int wsum[16];
    int tid = threadIdx.x, wave = tid >> 6, lane = tid & 63;
    int i = blockIdx.x * 1024 + tid;
    int c = (i < N) ? counts[i] : 0;
    int x = c;
    #pragma unroll
    for (int off = 1; off < 64; off <<= 1) {
        int v = __shfl_up(x, off);
        if (lane >= off) x += v;
    }
    if (lane == 63) wsum[wave] = x;
    __syncthreads();
    int pre = 0, tot = 0;
    #pragma unroll
    for (int w = 0; w < 16; ++w) {
        int s = wsum[w];
        tot += s;
        if (w < wave) pre += s;
    }
    if (i < N) {
        rowstart[i] = pre + x - c;
        dinv[i] = rsqrtf((float)c + 1.0f);
    }
    if (tid == 0) psum[blockIdx.x] = tot;
}

__global__ void scan_s2(int* __restrict__ psum, int nchunk,
                        int* __restrict__ rowstart, int N) {
    __shared__ int wsum[16];
    int tid = threadIdx.x, wave = tid >> 6, lane = tid & 63;
    int v = (tid < nchunk) ? psum[tid] : 0;
    int x = v;
    #pragma unroll
    for (int off = 1; off < 64; off <<= 1) {
        int s = __shfl_up(x, off);
        if (lane >= off) x += s;
    }
    if (lane == 63) wsum[wave] = x;
    __syncthreads();
    int pre = 0, tot = 0;
    #pragma unroll
    for (int w = 0; w < 16; ++w) {
        int s = wsum[w];
        tot += s;
        if (w < wave) pre += s;
    }
    if (tid < nchunk) psum[tid] = pre + x - v;
    if (tid == 0) rowstart[N] = tot;
}

__global__ void scan_s3(int* __restrict__ rowstart, const int* __restrict__ psum,
                        int N, int* __restrict__ cursor) {
    int i = blockIdx.x * 1024 + threadIdx.x;
    if (i < N) {
        int r = rowstart[i] + psum[blockIdx.x];
        rowstart[i] = r;
        cursor[i] = r;
    }
}

__global__ void fill_csr(const int* __restrict__ src, const int* __restrict__ dst, int E,
                         int* __restrict__ cursor, int* __restrict__ csr_src) {
    int e = blockIdx.x * 256 + threadIdx.x;
    if (e < E) {
        int p = atomicAdd(&cursor[dst[e]], 1);
        csr_src[p] = src[e];
    }
}

// ---------------- fp32 node GEMM: t = in @ W, stored bf16 ----------------

__global__ __launch_bounds__(256) void node_gemm(const float* __restrict__ in,
                                                 const float* __restrict__ W,
                                                 unsigned short* __restrict__ outb, int N) {
    __shared__ __align__(16) float rl[64][128];
    int tid = threadIdx.x;
    int rowbase = blockIdx.x * 64;
    #pragma unroll
    for (int p = 0; p < 8; ++p) {
        int idx = p * 256 + tid;
        int r = idx >> 5, c4 = (idx & 31) * 4;
        int row = rowbase + r;
        if (row >= N) row = N - 1;
        *(float4*)&rl[r][c4] = *(const float4*)(in + (size_t)row * 128 + c4);
    }
    __syncthreads();
    int rg = tid >> 5, cg = tid & 31, f0 = cg * 4;
    f32x4 acc[8];
    #pragma unroll
    for (int i = 0; i < 8; ++i) acc[i] = (f32x4){0.f, 0.f, 0.f, 0.f};
    for (int k = 0; k < 128; k += 4) {
        f32x4 w0 = *(const f32x4*)&W[(k + 0) * 128 + f0];
        f32x4 w1 = *(const f32x4*)&W[(k + 1) * 128 + f0];
        f32x4 w2 = *(const f32x4*)&W[(k + 2) * 128 + f0];
        f32x4 w3 = *(const f32x4*)&W[(k + 3) * 128 + f0];
        #pragma unroll
        for (int i = 0; i < 8; ++i) {
            f32x4 r4 = *(const f32x4*)&rl[rg * 8 + i][k];
            acc[i] += r4[0] * w0;
            acc[i] += r4[1] * w1;
            acc[i] += r4[2] * w2;
            acc[i] += r4[3] * w3;
        }
    }
    #pragma unroll
    for (int i = 0; i < 8; ++i) {
        int row = rowbase + rg * 8 + i;
        if (row < N) {
            unsigned int u0 = (unsigned int)f2b(acc[i][0]) | ((unsigned int)f2b(acc[i][1]) << 16);
            unsigned int u1 = (unsigned int)f2b(acc[i][2]) | ((unsigned int)f2b(acc[i][3]) << 16);
            *(uint2*)(outb + (size_t)row * 128 + f0) = make_uint2(u0, u1);
        }
    }
}

// ---------------- GCN aggregation: bf16 gather, fp32 math ----------------

template <int RELU, int BF16OUT>
__global__ __launch_bounds__(256) void aggregate(
        const unsigned short* __restrict__ tb, const int* __restrict__ rowstart,
        const int* __restrict__ csr_src, const float* __restrict__ dinv,
        const float* __restrict__ bias, float* __restrict__ hout,
        unsigned short* __restrict__ hb_out, int N) {
    int tid = threadIdx.x;
    int node = blockIdx.x * 8 + (tid >> 5);
    if (node >= N) return;
    int c = (tid & 31) * 4;
    float di = dinv[node];
    f32x4 self = b2f4(*(const ushort4*)(tb + (size_t)node * 128 + c));
    f32x4 acc = *(const f32x4*)(bias + c) + (di * di) * self;
    int rs = rowstart[node], re = rowstart[node + 1];
    int e = rs;
    for (; e + 1 < re; e += 2) {
        int s0 = csr_src[e], s1 = csr_src[e + 1];
        float n0 = dinv[s0] * di;
        float n1 = dinv[s1] * di;
        f32x4 t0 = b2f4(*(const ushort4*)(tb + (size_t)s0 * 128 + c));
        f32x4 t1 = b2f4(*(const ushort4*)(tb + (size_t)s1 * 128 + c));
        acc += n0 * t0;
        acc += n1 * t1;
    }
    if (e < re) {
        int s0 = csr_src[e];
        acc += (dinv[s0] * di) * b2f4(*(const ushort4*)(tb + (size_t)s0 * 128 + c));
    }
    if (RELU) {
        #pragma unroll
        for (int j = 0; j < 4; ++j) acc[j] = fmaxf(acc[j], 0.f);
    }
    if (BF16OUT) {
        unsigned int u0 = (unsigned int)f2b(acc[0]) | ((unsigned int)f2b(acc[1]) << 16);
        unsigned int u1 = (unsigned int)f2b(acc[2]) | ((unsigned int)f2b(acc[3]) << 16);
        *(uint2*)(hb_out + (size_t)node * 128 + c) = make_uint2(u0, u1);
    } else {
        *(f32x4*)(hout + (size_t)node * 128 + c) = acc;
    }
}

// ---------------- uv precompute: bf16 out ----------------
// uv[i][0:128]=h3@Wm1_top, uv[i][128:256]=h3@Wm1_bot

__global__ __launch_bounds__(256) void uv_gemm(const unsigned short* __restrict__ h3b,
                                               const float* __restrict__ Wm1,
                                               unsigned short* __restrict__ uvb, int N) {
    __shared__ __align__(16) unsigned short hl[64][136];
    int tid = threadIdx.x;
    int wid = tid >> 6, lane = tid & 63;
    int lg = lane >> 4, l15 = lane & 15;
    int tilebase = blockIdx.x * 64;

    bf16x8 a[4][4];
    #pragma unroll
    for (int mt = 0; mt < 4; ++mt) {
        int jc = wid * 64 + mt * 16 + l15;
        int koff = (jc >> 7) * 128;
        int col = jc & 127;
        #pragma unroll
        for (int kk = 0; kk < 4; ++kk) {
            bf16x8 af;
            #pragma unroll
            for (int ee = 0; ee < 8; ++ee)
                af[ee] = (short)f2b(Wm1[(size_t)(koff + kk * 32 + lg * 8 + ee) * 128 + col]);
            a[mt][kk] = af;
        }
    }

    #pragma unroll
    for (int p = 0; p < 4; ++p) {
        int idx = p * 256 + tid;
        int r = idx >> 4, ci = idx & 15;
        int row = tilebase + r;
        if (row >= N) row = N - 1;
        uint4 v = *(const uint4*)(h3b + (size_t)row * 128 + ci * 8);
        *(uint4*)&hl[r][ci * 8] = v;
    }
    __syncthreads();

    f32x4 acc[4][4];
    #pragma unroll
    for (int mt = 0; mt < 4; ++mt)
        #pragma unroll
        for (int nt = 0; nt < 4; ++nt) acc[mt][nt] = (f32x4){0.f, 0.f, 0.f, 0.f};
    #pragma unroll
    for (int kk = 0; kk < 4; ++kk) {
        #pragma unroll
        for (int nt = 0; nt < 4; ++nt) {
            bf16x8 b = *(const bf16x8*)&hl[nt * 16 + l15][kk * 32 + lg * 8];
            #pragma unroll
            for (int mt = 0; mt < 4; ++mt)
                acc[mt][nt] = __builtin_amdgcn_mfma_f32_16x16x32_bf16(a[mt][kk], b, acc[mt][nt], 0, 0, 0);
        }
    }
    #pragma unroll
    for (int mt = 0; mt < 4; ++mt) {
        int jc = wid * 64 + mt * 16 + lg * 4;
        #pragma unroll
        for (int nt = 0; nt < 4; ++nt) {
            int node = tilebase + nt * 16 + l15;
            if (node < N) {
                unsigned int u0 = (unsigned int)f2b(acc[mt][nt][0]) | ((unsigned int)f2b(acc[mt][nt][1]) << 16);
                unsigned int u1 = (unsigned int)f2b(acc[mt][nt][2]) | ((unsigned int)f2b(acc[mt][nt][3]) << 16);
                *(uint2*)(uvb + (size_t)node * 256 + jc) = make_uint2(u0, u1);
            }
        }
    }
}

// ---------------- edge head: z = relu(u[src]+v[dst]+bm1); out = z@Wm2+bm2 ----------------

__global__ __launch_bounds__(256, 3) void edge_head2(
        const unsigned short* __restrict__ uvb, const int* __restrict__ src,
        const int* __restrict__ dst, const float* __restrict__ bm1,
        const float* __restrict__ Wm2, const float* __restrict__ bm2,
        float* __restrict__ out, int E, int ntiles) {
    __shared__ __align__(16) unsigned short zl[64][136];
    int tid = threadIdx.x;
    int wid = tid >> 6, lane = tid & 63;
    int lg = lane >> 4, l15 = lane & 15;
    int es = tid >> 4;
    int ci = tid & 15;
    int c0 = ci * 8;

    bf16x8 a2[2][4];
    float b2v[2][4];
    #pragma unroll
    for (int mt = 0; mt < 2; ++mt) {
        int m = wid * 32 + mt * 16 + l15;
        #pragma unroll
        for (int kk = 0; kk < 4; ++kk) {
            bf16x8 af;
            #pragma unroll
            for (int ee = 0; ee < 8; ++ee)
                af[ee] = (short)f2b(Wm2[(size_t)(kk * 32 + lg * 8 + ee) * 128 + m]);
            a2[mt][kk] = af;
        }
        #pragma unroll
        for (int r = 0; r < 4; ++r)
            b2v[mt][r] = bm2[wid * 32 + mt * 16 + lg * 4 + r];
    }
    float bm1v[8];
    #pragma unroll
    for (int j = 0; j < 8; ++j) bm1v[j] = bm1[c0 + j];

    for (int tile = blockIdx.x; tile < ntiles; tile += gridDim.x) {
        __syncthreads();
        // ---- stage z: 4 passes x 16 edges; bf16 u,v gather ----
        #pragma unroll
        for (int p = 0; p < 4; ++p) {
            int eg = tile * 64 + p * 16 + es;
            if (eg >= E) eg = E - 1;
            int s = src[eg], d = dst[eg];
            uint4 uu = *(const uint4*)(uvb + (size_t)s * 256 + c0);
            uint4 vv = *(const uint4*)(uvb + (size_t)d * 256 + 128 + c0);
            unsigned int w[4];
            {
                float z0 = fmaxf(b2f((unsigned short)(uu.x)) + b2f((unsigned short)(vv.x)) + bm1v[0], 0.f);
                float z1 = fmaxf(b2f((unsigned short)(uu.x >> 16)) + b2f((unsigned short)(vv.x >> 16)) + bm1v[1], 0.f);
                float z2 = fmaxf(b2f((unsigned short)(uu.y)) + b2f((unsigned short)(vv.y)) + bm1v[2], 0.f);
                float z3 = fmaxf(b2f((unsigned short)(uu.y >> 16)) + b2f((unsigned short)(vv.y >> 16)) + bm1v[3], 0.f);
                float z4 = fmaxf(b2f((unsigned short)(uu.z)) + b2f((unsigned short)(vv.z)) + bm1v[4], 0.f);
                float z5 = fmaxf(b2f((unsigned short)(uu.z >> 16)) + b2f((unsigned short)(vv.z >> 16)) + bm1v[5], 0.f);
                float z6 = fmaxf(b2f((unsigned short)(uu.w)) + b2f((unsigned short)(vv.w)) + bm1v[6], 0.f);
                float z7 = fmaxf(b2f((unsigned short)(uu.w >> 16)) + b2f((unsigned short)(vv.w >> 16)) + bm1v[7], 0.f);
                w[0] = (unsigned int)f2b(z0) | ((unsigned int)f2b(z1) << 16);
                w[1] = (unsigned int)f2b(z2) | ((unsigned int)f2b(z3) << 16);
                w[2] = (unsigned int)f2b(z4) | ((unsigned int)f2b(z5) << 16);
                w[3] = (unsigned int)f2b(z6) | ((unsigned int)f2b(z7) << 16);
            }
            *(uint4*)&zl[p * 16 + es][c0] = make_uint4(w[0], w[1], w[2], w[3]);
        }
        __syncthreads();

        // ---- GEMM2 ----
        f32x4 c2[2][4];
        #pragma unroll
        for (int mt = 0; mt < 2; ++mt)
            #pragma unroll
            for (int nt = 0; nt < 4; ++nt) c2[mt][nt] = (f32x4){0.f, 0.f, 0.f, 0.f};
        #pragma unroll
        for (int kk = 0; kk < 4; ++kk) {
            #pragma unroll
            for (int nt = 0; nt < 4; ++nt) {
                bf16x8 b = *(const bf16x8*)&zl[nt * 16 + l15][kk * 32 + lg * 8];
                c2[0][nt] = __builtin_amdgcn_mfma_f32_16x16x32_bf16(a2[0][kk], b, c2[0][nt], 0, 0, 0);
                c2[1][nt] = __builtin_amdgcn_mfma_f32_16x16x32_bf16(a2[1][kk], b, c2[1][nt], 0, 0, 0);
            }
        }
        #pragma unroll
        for (int mt = 0; mt < 2; ++mt) {
            #pragma unroll
            for (int nt = 0; nt < 4; ++nt) {
                int eg = tile * 64 + nt * 16 + l15;
                if (eg < E) {
                    f32x4 o;
                    #pragma unroll
                    for (int r = 0; r < 4; ++r) o[r] = c2[mt][nt][r] + b2v[mt][r];
                    *(f32x4*)(out + (size_t)eg * 128 + wid * 32 + mt * 16 + lg * 4) = o;
                }
            }
        }
    }
}

// ---------------- launch ----------------

extern "C" void kernel_launch(void* const* d_in, const int* in_sizes, int n_in,
                              void* d_out, int out_size, void* d_ws, size_t ws_size,
                              hipStream_t stream) {
    const float* x  = (const float*)d_in[0];
    const int*   ei = (const int*)d_in[1];
    const float* W1 = (const float*)d_in[2];
    const float* b1 = (const float*)d_in[3];
    const float* W2 = (const float*)d_in[4];
    const float* b2 = (const float*)d_in[5];
    const float* W3 = (const float*)d_in[6];
    const float* b3 = (const float*)d_in[7];
    const float* Wm1 = (const float*)d_in[8];
    const float* bm1 = (const float*)d_in[9];
    const float* Wm2 = (const float*)d_in[10];
    const float* bm2 = (const float*)d_in[11];
    float* out = (float*)d_out;

    const int N = in_sizes[0] / 128;
    const int E = in_sizes[1] / 2;
    const int* src = ei;
    const int* dstp = ei + E;

    uintptr_t base = (uintptr_t)d_ws;
    auto alloc = [&](size_t bytes) -> void* {
        uintptr_t p = base;
        base += (bytes + 255) & ~(uintptr_t)255;
        return (void*)p;
    };
    int*   counts   = (int*)alloc((size_t)(N + 1) * 4);
    int*   rowstart = (int*)alloc((size_t)(N + 1) * 4);
    int*   cursor   = (int*)alloc((size_t)N * 4);
    float* dinv     = (float*)alloc((size_t)N * 4);
    int*   psum     = (int*)alloc(4096);
    int*   csr      = (int*)alloc((size_t)E * 4);
    unsigned short* tb  = (unsigned short*)alloc((size_t)N * 128 * 2);
    float* h        = (float*)alloc((size_t)N * 128 * 4);
    unsigned short* h3b = (unsigned short*)alloc((size_t)N * 128 * 2);
    unsigned short* uvb = (unsigned short*)alloc((size_t)N * 256 * 2);
    (void)ws_size; (void)n_in; (void)out_size;

    hipMemsetAsync(counts, 0, (size_t)(N + 1) * 4, stream);

    int egrid = (E + 255) / 256;
    int nchunk = (N + 1023) / 1024;
    count_deg<<<egrid, 256, 0, stream>>>(dstp, E, counts);
    scan_s1<<<nchunk, 1024, 0, stream>>>(counts, N, rowstart, dinv, psum);
    scan_s2<<<1, 1024, 0, stream>>>(psum, nchunk, rowstart, N);
    scan_s3<<<nchunk, 1024, 0, stream>>>(rowstart, psum, N, cursor);
    fill_csr<<<egrid, 256, 0, stream>>>(src, dstp, E, cursor, csr);

    int ggrid = (N + 63) / 64;
    int agrid = (N + 7) / 8;
    node_gemm<<<ggrid, 256, 0, stream>>>(x, W1, tb, N);
    aggregate<1, 0><<<agrid, 256, 0, stream>>>(tb, rowstart, csr, dinv, b1, h, nullptr, N);
    node_gemm<<<ggrid, 256, 0, stream>>>(h, W2, tb, N);
    aggregate<1, 0><<<agrid, 256, 0, stream>>>(tb, rowstart, csr, dinv, b2, h, nullptr, N);
    node_gemm<<<ggrid, 256, 0, stream>>>(h, W3, tb, N);
    aggregate<0, 1><<<agrid, 256, 0, stream>>>(tb, rowstart, csr, dinv, b3, nullptr, h3b, N);

    uv_gemm<<<ggrid, 256, 0, stream>>>(h3b, Wm1, uvb, N);

    int ntiles = (E + 63) / 64;
    int hgrid = ntiles < 1024 ? ntiles : 1024;
    edge_head2<<<hgrid, 256, 0, stream>>>(uvb, src, dstp, bm1, Wm2, bm2, out, E, ntiles);
}

// Round 4
// 464.056 us; speedup vs baseline: 1.4041x; 1.0814x over previous
//
#include <hip/hip_runtime.h>
#include <stdint.h>

typedef __attribute__((ext_vector_type(8))) short bf16x8;
typedef __attribute__((ext_vector_type(4))) float f32x4;

static __device__ __forceinline__ unsigned short f2b(float f) {
    unsigned int u = __float_as_uint(f);
    unsigned int r = u + 0x7fffu + ((u >> 16) & 1u);   // RNE
    return (unsigned short)(r >> 16);
}
static __device__ __forceinline__ float b2f(unsigned short u) {
    return __uint_as_float((unsigned int)u << 16);
}
static __device__ __forceinline__ f32x4 b2f4(ushort4 u) {
    f32x4 r;
    r[0] = b2f(u.x); r[1] = b2f(u.y); r[2] = b2f(u.z); r[3] = b2f(u.w);
    return r;
}

// ---------------- CSR build ----------------

__global__ void count_deg(const int* __restrict__ dst, int E, int* __restrict__ counts) {
    int e = blockIdx.x * 256 + threadIdx.x;
    if (e < E) atomicAdd(&counts[dst[e]], 1);
}

__global__ void scan_s1(const int* __restrict__ counts, int N,
                        int* __restrict__ rowstart, float* __restrict__ dinv,
                        int* __restrict__ psum) {
    __shared__ int wsum[16];
    int tid = threadIdx.x, wave = tid >> 6, lane = tid & 63;
    int i = blockIdx.x * 1024 + tid;
    int c = (i < N) ? counts[i] : 0;
    int x = c;
    #pragma unroll
    for (int off = 1; off < 64; off <<= 1) {
        int v = __shfl_up(x, off);
        if (lane >= off) x += v;
    }
    if (lane == 63) wsum[wave] = x;
    __syncthreads();
    int pre = 0, tot = 0;
    #pragma unroll
    for (int w = 0; w < 16; ++w) {
        int s = wsum[w];
        tot += s;
        if (w < wave) pre += s;
    }
    if (i < N) {
        rowstart[i] = pre + x - c;
        dinv[i] = rsqrtf((float)c + 1.0f);
    }
    if (tid == 0) psum[blockIdx.x] = tot;
}

__global__ void scan_s2(int* __restrict__ psum, int nchunk,
                        int* __restrict__ rowstart, int N) {
    __shared__ int wsum[16];
    int tid = threadIdx.x, wave = tid >> 6, lane = tid & 63;
    int v = (tid < nchunk) ? psum[tid] : 0;
    int x = v;
    #pragma unroll
    for (int off = 1; off < 64; off <<= 1) {
        int s = __shfl_up(x, off);
        if (lane >= off) x += s;
    }
    if (lane == 63) wsum[wave] = x;
    __syncthreads();
    int pre = 0, tot = 0;
    #pragma unroll
    for (int w = 0; w < 16; ++w) {
        int s = wsum[w];
        tot += s;
        if (w < wave) pre += s;
    }
    if (tid < nchunk) psum[tid] = pre + x - v;
    if (tid == 0) rowstart[N] = tot;
}

__global__ void scan_s3(int* __restrict__ rowstart, const int* __restrict__ psum,
                        int N, int* __restrict__ cursor) {
    int i = blockIdx.x * 1024 + threadIdx.x;
    if (i < N) {
        int r = rowstart[i] + psum[blockIdx.x];
        rowstart[i] = r;
        cursor[i] = r;
    }
}

__global__ void fill_csr(const int* __restrict__ src, const int* __restrict__ dst, int E,
                         int* __restrict__ cursor, int* __restrict__ csr_src,
                         int* __restrict__ csr_dst, int* __restrict__ csr_eid) {
    int e = blockIdx.x * 256 + threadIdx.x;
    if (e < E) {
        int d = dst[e];
        int p = atomicAdd(&cursor[d], 1);
        csr_src[p] = src[e];
        csr_dst[p] = d;
        csr_eid[p] = e;
    }
}

// ---------------- node GEMM via MFMA: t = bf16(in) @ bf16(W), fp32 accum, bf16 out ----

template <int IN_F32>
__global__ __launch_bounds__(256) void node_mfma(const void* __restrict__ inp,
                                                 const float* __restrict__ W,
                                                 unsigned short* __restrict__ outb, int N) {
    __shared__ __align__(16) unsigned short hl[64][136];
    int tid = threadIdx.x;
    int wid = tid >> 6, lane = tid & 63;
    int lg = lane >> 4, l15 = lane & 15;
    int tilebase = blockIdx.x * 64;

    // A fragments: A[m=col][k] = W[k][col]
    bf16x8 a[2][4];
    #pragma unroll
    for (int mt = 0; mt < 2; ++mt) {
        int col = wid * 32 + mt * 16 + l15;
        #pragma unroll
        for (int kk = 0; kk < 4; ++kk) {
            bf16x8 af;
            #pragma unroll
            for (int ee = 0; ee < 8; ++ee)
                af[ee] = (short)f2b(W[(size_t)(kk * 32 + lg * 8 + ee) * 128 + col]);
            a[mt][kk] = af;
        }
    }

    // stage 64 input rows as bf16
    #pragma unroll
    for (int p = 0; p < 4; ++p) {
        int idx = p * 256 + tid;
        int r = idx >> 4, ci = idx & 15;
        int row = tilebase + r;
        if (row >= N) row = N - 1;
        if (IN_F32) {
            const float* ip = (const float*)inp + (size_t)row * 128 + ci * 8;
            f32x4 x0 = *(const f32x4*)ip;
            f32x4 x1 = *(const f32x4*)(ip + 4);
            uint4 v;
            v.x = (unsigned int)f2b(x0[0]) | ((unsigned int)f2b(x0[1]) << 16);
            v.y = (unsigned int)f2b(x0[2]) | ((unsigned int)f2b(x0[3]) << 16);
            v.z = (unsigned int)f2b(x1[0]) | ((unsigned int)f2b(x1[1]) << 16);
            v.w = (unsigned int)f2b(x1[2]) | ((unsigned int)f2b(x1[3]) << 16);
            *(uint4*)&hl[r][ci * 8] = v;
        } else {
            *(uint4*)&hl[r][ci * 8] =
                *(const uint4*)((const unsigned short*)inp + (size_t)row * 128 + ci * 8);
        }
    }
    __syncthreads();

    f32x4 acc[2][4];
    #pragma unroll
    for (int mt = 0; mt < 2; ++mt)
        #pragma unroll
        for (int nt = 0; nt < 4; ++nt) acc[mt][nt] = (f32x4){0.f, 0.f, 0.f, 0.f};
    #pragma unroll
    for (int kk = 0; kk < 4; ++kk) {
        #pragma unroll
        for (int nt = 0; nt < 4; ++nt) {
            bf16x8 b = *(const bf16x8*)&hl[nt * 16 + l15][kk * 32 + lg * 8];
            acc[0][nt] = __builtin_amdgcn_mfma_f32_16x16x32_bf16(a[0][kk], b, acc[0][nt], 0, 0, 0);
            acc[1][nt] = __builtin_amdgcn_mfma_f32_16x16x32_bf16(a[1][kk], b, acc[1][nt], 0, 0, 0);
        }
    }
    #pragma unroll
    for (int mt = 0; mt < 2; ++mt) {
        int j = wid * 32 + mt * 16 + lg * 4;
        #pragma unroll
        for (int nt = 0; nt < 4; ++nt) {
            int node = tilebase + nt * 16 + l15;
            if (node < N) {
                unsigned int u0 = (unsigned int)f2b(acc[mt][nt][0]) | ((unsigned int)f2b(acc[mt][nt][1]) << 16);
                unsigned int u1 = (unsigned int)f2b(acc[mt][nt][2]) | ((unsigned int)f2b(acc[mt][nt][3]) << 16);
                *(uint2*)(outb + (size_t)node * 128 + j) = make_uint2(u0, u1);
            }
        }
    }
}

// ---------------- GCN aggregation: bf16 gather, fp32 math, bf16 out ----------------

template <int RELU>
__global__ __launch_bounds__(256) void aggregate(
        const unsigned short* __restrict__ tb, const int* __restrict__ rowstart,
        const int* __restrict__ csr_src, const float* __restrict__ dinv,
        const float* __restrict__ bias, unsigned short* __restrict__ hb, int N) {
    int tid = threadIdx.x;
    int node = blockIdx.x * 8 + (tid >> 5);
    if (node >= N) return;
    int c = (tid & 31) * 4;
    float di = dinv[node];
    f32x4 self = b2f4(*(const ushort4*)(tb + (size_t)node * 128 + c));
    f32x4 acc = *(const f32x4*)(bias + c) + (di * di) * self;
    int rs = rowstart[node], re = rowstart[node + 1];
    int e = rs;
    for (; e + 1 < re; e += 2) {
        int s0 = csr_src[e], s1 = csr_src[e + 1];
        float n0 = dinv[s0] * di;
        float n1 = dinv[s1] * di;
        f32x4 t0 = b2f4(*(const ushort4*)(tb + (size_t)s0 * 128 + c));
        f32x4 t1 = b2f4(*(const ushort4*)(tb + (size_t)s1 * 128 + c));
        acc += n0 * t0;
        acc += n1 * t1;
    }
    if (e < re) {
        int s0 = csr_src[e];
        acc += (dinv[s0] * di) * b2f4(*(const ushort4*)(tb + (size_t)s0 * 128 + c));
    }
    if (RELU) {
        #pragma unroll
        for (int j = 0; j < 4; ++j) acc[j] = fmaxf(acc[j], 0.f);
    }
    unsigned int u0 = (unsigned int)f2b(acc[0]) | ((unsigned int)f2b(acc[1]) << 16);
    unsigned int u1 = (unsigned int)f2b(acc[2]) | ((unsigned int)f2b(acc[3]) << 16);
    *(uint2*)(hb + (size_t)node * 128 + c) = make_uint2(u0, u1);
}

// ---------------- uv precompute: bf16 out ----------------
// uv[i][0:128]=h3@Wm1_top, uv[i][128:256]=h3@Wm1_bot

__global__ __launch_bounds__(256) void uv_gemm(const unsigned short* __restrict__ h3b,
                                               const float* __restrict__ Wm1,
                                               unsigned short* __restrict__ uvb, int N) {
    __shared__ __align__(16) unsigned short hl[64][136];
    int tid = threadIdx.x;
    int wid = tid >> 6, lane = tid & 63;
    int lg = lane >> 4, l15 = lane & 15;
    int tilebase = blockIdx.x * 64;

    bf16x8 a[4][4];
    #pragma unroll
    for (int mt = 0; mt < 4; ++mt) {
        int jc = wid * 64 + mt * 16 + l15;
        int koff = (jc >> 7) * 128;
        int col = jc & 127;
        #pragma unroll
        for (int kk = 0; kk < 4; ++kk) {
            bf16x8 af;
            #pragma unroll
            for (int ee = 0; ee < 8; ++ee)
                af[ee] = (short)f2b(Wm1[(size_t)(koff + kk * 32 + lg * 8 + ee) * 128 + col]);
            a[mt][kk] = af;
        }
    }

    #pragma unroll
    for (int p = 0; p < 4; ++p) {
        int idx = p * 256 + tid;
        int r = idx >> 4, ci = idx & 15;
        int row = tilebase + r;
        if (row >= N) row = N - 1;
        uint4 v = *(const uint4*)(h3b + (size_t)row * 128 + ci * 8);
        *(uint4*)&hl[r][ci * 8] = v;
    }
    __syncthreads();

    f32x4 acc[4][4];
    #pragma unroll
    for (int mt = 0; mt < 4; ++mt)
        #pragma unroll
        for (int nt = 0; nt < 4; ++nt) acc[mt][nt] = (f32x4){0.f, 0.f, 0.f, 0.f};
    #pragma unroll
    for (int kk = 0; kk < 4; ++kk) {
        #pragma unroll
        for (int nt = 0; nt < 4; ++nt) {
            bf16x8 b = *(const bf16x8*)&hl[nt * 16 + l15][kk * 32 + lg * 8];
            #pragma unroll
            for (int mt = 0; mt < 4; ++mt)
                acc[mt][nt] = __builtin_amdgcn_mfma_f32_16x16x32_bf16(a[mt][kk], b, acc[mt][nt], 0, 0, 0);
        }
    }
    #pragma unroll
    for (int mt = 0; mt < 4; ++mt) {
        int jc = wid * 64 + mt * 16 + lg * 4;
        #pragma unroll
        for (int nt = 0; nt < 4; ++nt) {
            int node = tilebase + nt * 16 + l15;
            if (node < N) {
                unsigned int u0 = (unsigned int)f2b(acc[mt][nt][0]) | ((unsigned int)f2b(acc[mt][nt][1]) << 16);
                unsigned int u1 = (unsigned int)f2b(acc[mt][nt][2]) | ((unsigned int)f2b(acc[mt][nt][3]) << 16);
                *(uint2*)(uvb + (size_t)node * 256 + jc) = make_uint2(u0, u1);
            }
        }
    }
}

// ---------------- edge head (CSR order): z = relu(u[src]+v[dst]+bm1); out[eid] = z@Wm2+bm2 ----

__global__ __launch_bounds__(256, 3) void edge_head3(
        const unsigned short* __restrict__ uvb, const int* __restrict__ csr_src,
        const int* __restrict__ csr_dst, const int* __restrict__ csr_eid,
        const float* __restrict__ bm1, const float* __restrict__ Wm2,
        const float* __restrict__ bm2, float* __restrict__ out, int E, int ntiles) {
    __shared__ __align__(16) unsigned short zl[64][136];
    __shared__ int eid_l[64];
    int tid = threadIdx.x;
    int wid = tid >> 6, lane = tid & 63;
    int lg = lane >> 4, l15 = lane & 15;
    int es = tid >> 4;
    int ci = tid & 15;
    int c0 = ci * 8;

    bf16x8 a2[2][4];
    float b2v[2][4];
    #pragma unroll
    for (int mt = 0; mt < 2; ++mt) {
        int m = wid * 32 + mt * 16 + l15;
        #pragma unroll
        for (int kk = 0; kk < 4; ++kk) {
            bf16x8 af;
            #pragma unroll
            for (int ee = 0; ee < 8; ++ee)
                af[ee] = (short)f2b(Wm2[(size_t)(kk * 32 + lg * 8 + ee) * 128 + m]);
            a2[mt][kk] = af;
        }
        #pragma unroll
        for (int r = 0; r < 4; ++r)
            b2v[mt][r] = bm2[wid * 32 + mt * 16 + lg * 4 + r];
    }
    float bm1v[8];
    #pragma unroll
    for (int j = 0; j < 8; ++j) bm1v[j] = bm1[c0 + j];

    for (int tile = blockIdx.x; tile < ntiles; tile += gridDim.x) {
        __syncthreads();
        // ---- stage z: 4 passes x 16 CSR slots ----
        #pragma unroll
        for (int p = 0; p < 4; ++p) {
            int slot = tile * 64 + p * 16 + es;
            int cs = (slot < E) ? slot : (E - 1);
            int s = csr_src[cs], d = csr_dst[cs];
            if (ci == 0) eid_l[p * 16 + es] = (slot < E) ? csr_eid[cs] : -1;
            uint4 uu = *(const uint4*)(uvb + (size_t)s * 256 + c0);
            uint4 vv = *(const uint4*)(uvb + (size_t)d * 256 + 128 + c0);
            unsigned int w[4];
            {
                float z0 = fmaxf(b2f((unsigned short)(uu.x)) + b2f((unsigned short)(vv.x)) + bm1v[0], 0.f);
                float z1 = fmaxf(b2f((unsigned short)(uu.x >> 16)) + b2f((unsigned short)(vv.x >> 16)) + bm1v[1], 0.f);
                float z2 = fmaxf(b2f((unsigned short)(uu.y)) + b2f((unsigned short)(vv.y)) + bm1v[2], 0.f);
                float z3 = fmaxf(b2f((unsigned short)(uu.y >> 16)) + b2f((unsigned short)(vv.y >> 16)) + bm1v[3], 0.f);
                float z4 = fmaxf(b2f((unsigned short)(uu.z)) + b2f((unsigned short)(vv.z)) + bm1v[4], 0.f);
                float z5 = fmaxf(b2f((unsigned short)(uu.z >> 16)) + b2f((unsigned short)(vv.z >> 16)) + bm1v[5], 0.f);
                float z6 = fmaxf(b2f((unsigned short)(uu.w)) + b2f((unsigned short)(vv.w)) + bm1v[6], 0.f);
                float z7 = fmaxf(b2f((unsigned short)(uu.w >> 16)) + b2f((unsigned short)(vv.w >> 16)) + bm1v[7], 0.f);
                w[0] = (unsigned int)f2b(z0) | ((unsigned int)f2b(z1) << 16);
                w[1] = (unsigned int)f2b(z2) | ((unsigned int)f2b(z3) << 16);
                w[2] = (unsigned int)f2b(z4) | ((unsigned int)f2b(z5) << 16);
                w[3] = (unsigned int)f2b(z6) | ((unsigned int)f2b(z7) << 16);
            }
            *(uint4*)&zl[p * 16 + es][c0] = make_uint4(w[0], w[1], w[2], w[3]);
        }
        __syncthreads();

        // ---- GEMM2 ----
        f32x4 c2[2][4];
        #pragma unroll
        for (int mt = 0; mt < 2; ++mt)
            #pragma unroll
            for (int nt = 0; nt < 4; ++nt) c2[mt][nt] = (f32x4){0.f, 0.f, 0.f, 0.f};
        #pragma unroll
        for (int kk = 0; kk < 4; ++kk) {
            #pragma unroll
            for (int nt = 0; nt < 4; ++nt) {
                bf16x8 b = *(const bf16x8*)&zl[nt * 16 + l15][kk * 32 + lg * 8];
                c2[0][nt] = __builtin_amdgcn_mfma_f32_16x16x32_bf16(a2[0][kk], b, c2[0][nt], 0, 0, 0);
                c2[1][nt] = __builtin_amdgcn_mfma_f32_16x16x32_bf16(a2[1][kk], b, c2[1][nt], 0, 0, 0);
            }
        }
        #pragma unroll
        for (int mt = 0; mt < 2; ++mt) {
            #pragma unroll
            for (int nt = 0; nt < 4; ++nt) {
                int eg = eid_l[nt * 16 + l15];
                if (eg >= 0) {
                    f32x4 o;
                    #pragma unroll
                    for (int r = 0; r < 4; ++r) o[r] = c2[mt][nt][r] + b2v[mt][r];
                    *(f32x4*)(out + (size_t)eg * 128 + wid * 32 + mt * 16 + lg * 4) = o;
                }
            }
        }
    }
}

// ---------------- launch ----------------

extern "C" void kernel_launch(void* const* d_in, const int* in_sizes, int n_in,
                              void* d_out, int out_size, void* d_ws, size_t ws_size,
                              hipStream_t stream) {
    const float* x  = (const float*)d_in[0];
    const int*   ei = (const int*)d_in[1];
    const float* W1 = (const float*)d_in[2];
    const float* b1 = (const float*)d_in[3];
    const float* W2 = (const float*)d_in[4];
    const float* b2 = (const float*)d_in[5];
    const float* W3 = (const float*)d_in[6];
    const float* b3 = (const float*)d_in[7];
    const float* Wm1 = (const float*)d_in[8];
    const float* bm1 = (const float*)d_in[9];
    const float* Wm2 = (const float*)d_in[10];
    const float* bm2 = (const float*)d_in[11];
    float* out = (float*)d_out;

    const int N = in_sizes[0] / 128;
    const int E = in_sizes[1] / 2;
    const int* src = ei;
    const int* dstp = ei + E;

    uintptr_t base = (uintptr_t)d_ws;
    auto alloc = [&](size_t bytes) -> void* {
        uintptr_t p = base;
        base += (bytes + 255) & ~(uintptr_t)255;
        return (void*)p;
    };
    int*   counts   = (int*)alloc((size_t)(N + 1) * 4);
    int*   rowstart = (int*)alloc((size_t)(N + 1) * 4);
    int*   cursor   = (int*)alloc((size_t)N * 4);
    float* dinv     = (float*)alloc((size_t)N * 4);
    int*   psum     = (int*)alloc(4096);
    int*   csr_s    = (int*)alloc((size_t)E * 4);
    int*   csr_d    = (int*)alloc((size_t)E * 4);
    int*   csr_e    = (int*)alloc((size_t)E * 4);
    unsigned short* tb  = (unsigned short*)alloc((size_t)N * 128 * 2);
    unsigned short* hb  = (unsigned short*)alloc((size_t)N * 128 * 2);
    unsigned short* uvb = (unsigned short*)alloc((size_t)N * 256 * 2);
    (void)ws_size; (void)n_in; (void)out_size;

    hipMemsetAsync(counts, 0, (size_t)(N + 1) * 4, stream);

    int egrid = (E + 255) / 256;
    int nchunk = (N + 1023) / 1024;
    count_deg<<<egrid, 256, 0, stream>>>(dstp, E, counts);
    scan_s1<<<nchunk, 1024, 0, stream>>>(counts, N, rowstart, dinv, psum);
    scan_s2<<<1, 1024, 0, stream>>>(psum, nchunk, rowstart, N);
    scan_s3<<<nchunk, 1024, 0, stream>>>(rowstart, psum, N, cursor);
    fill_csr<<<egrid, 256, 0, stream>>>(src, dstp, E, cursor, csr_s, csr_d, csr_e);

    int ggrid = (N + 63) / 64;
    int agrid = (N + 7) / 8;
    node_mfma<1><<<ggrid, 256, 0, stream>>>(x, W1, tb, N);
    aggregate<1><<<agrid, 256, 0, stream>>>(tb, rowstart, csr_s, dinv, b1, hb, N);
    node_mfma<0><<<ggrid, 256, 0, stream>>>(hb, W2, tb, N);
    aggregate<1><<<agrid, 256, 0, stream>>>(tb, rowstart, csr_s, dinv, b2, hb, N);
    node_mfma<0><<<ggrid, 256, 0, stream>>>(hb, W3, tb, N);
    aggregate<0><<<agrid, 256, 0, stream>>>(tb, rowstart, csr_s, dinv, b3, hb, N);

    uv_gemm<<<ggrid, 256, 0, stream>>>(hb, Wm1, uvb, N);

    int ntiles = (E + 63) / 64;
    int hgrid = ntiles < 1024 ? ntiles : 1024;
    edge_head3<<<hgrid, 256, 0, stream>>>(uvb, csr_s, csr_d, csr_e, bm1, Wm2, bm2, out, E, ntiles);
}

// Round 5
// 431.236 us; speedup vs baseline: 1.5109x; 1.0761x over previous
//
#include <hip/hip_runtime.h>
#include <stdint.h>

typedef __attribute__((ext_vector_type(8))) short bf16x8;
typedef __attribute__((ext_vector_type(4))) float f32x4;

static __device__ __forceinline__ unsigned short f2b(float f) {
    unsigned int u = __float_as_uint(f);
    unsigned int r = u + 0x7fffu + ((u >> 16) & 1u);   // RNE
    return (unsigned short)(r >> 16);
}
static __device__ __forceinline__ float b2f(unsigned short u) {
    return __uint_as_float((unsigned int)u << 16);
}
static __device__ __forceinline__ f32x4 b2f4(ushort4 u) {
    f32x4 r;
    r[0] = b2f(u.x); r[1] = b2f(u.y); r[2] = b2f(u.z); r[3] = b2f(u.w);
    return r;
}

// ---------------- CSR build ----------------

__global__ void count_deg(const int* __restrict__ dst, int E, int* __restrict__ counts) {
    int e = blockIdx.x * 256 + threadIdx.x;
    if (e < E) atomicAdd(&counts[dst[e]], 1);
}

__global__ void scan_s1(const int* __restrict__ counts, int N,
                        int* __restrict__ rowstart, float* __restrict__ dinv,
                        int* __restrict__ psum) {
    __shared__ int wsum[16];
    int tid = threadIdx.x, wave = tid >> 6, lane = tid & 63;
    int i = blockIdx.x * 1024 + tid;
    int c = (i < N) ? counts[i] : 0;
    int x = c;
    #pragma unroll
    for (int off = 1; off < 64; off <<= 1) {
        int v = __shfl_up(x, off);
        if (lane >= off) x += v;
    }
    if (lane == 63) wsum[wave] = x;
    __syncthreads();
    int pre = 0, tot = 0;
    #pragma unroll
    for (int w = 0; w < 16; ++w) {
        int s = wsum[w];
        tot += s;
        if (w < wave) pre += s;
    }
    if (i < N) {
        rowstart[i] = pre + x - c;
        dinv[i] = rsqrtf((float)c + 1.0f);
    }
    if (tid == 0) psum[blockIdx.x] = tot;
}

__global__ void scan_s2(int* __restrict__ psum, int nchunk,
                        int* __restrict__ rowstart, int N) {
    __shared__ int wsum[16];
    int tid = threadIdx.x, wave = tid >> 6, lane = tid & 63;
    int v = (tid < nchunk) ? psum[tid] : 0;
    int x = v;
    #pragma unroll
    for (int off = 1; off < 64; off <<= 1) {
        int s = __shfl_up(x, off);
        if (lane >= off) x += s;
    }
    if (lane == 63) wsum[wave] = x;
    __syncthreads();
    int pre = 0, tot = 0;
    #pragma unroll
    for (int w = 0; w < 16; ++w) {
        int s = wsum[w];
        tot += s;
        if (w < wave) pre += s;
    }
    if (tid < nchunk) psum[tid] = pre + x - v;
    if (tid == 0) rowstart[N] = tot;
}

__global__ void scan_s3(int* __restrict__ rowstart, const int* __restrict__ psum,
                        int N, int* __restrict__ cursor) {
    int i = blockIdx.x * 1024 + threadIdx.x;
    if (i < N) {
        int r = rowstart[i] + psum[blockIdx.x];
        rowstart[i] = r;
        cursor[i] = r;
    }
}

__global__ void fill_csr(const int* __restrict__ src, const int* __restrict__ dst, int E,
                         int* __restrict__ cursor, int* __restrict__ csr_src,
                         int* __restrict__ csr_dst, int* __restrict__ csr_eid) {
    int e = blockIdx.x * 256 + threadIdx.x;
    if (e < E) {
        int d = dst[e];
        int p = atomicAdd(&cursor[d], 1);
        csr_src[p] = src[e];
        csr_dst[p] = d;
        csr_eid[p] = e;
    }
}

// ---------------- node GEMM via MFMA: t = bf16(in) @ bf16(W), fp32 accum, bf16 out ----

template <int IN_F32>
__global__ __launch_bounds__(256) void node_mfma(const void* __restrict__ inp,
                                                 const float* __restrict__ W,
                                                 unsigned short* __restrict__ outb, int N) {
    __shared__ __align__(16) unsigned short hl[64][136];
    int tid = threadIdx.x;
    int wid = tid >> 6, lane = tid & 63;
    int lg = lane >> 4, l15 = lane & 15;
    int tilebase = blockIdx.x * 64;

    bf16x8 a[2][4];
    #pragma unroll
    for (int mt = 0; mt < 2; ++mt) {
        int col = wid * 32 + mt * 16 + l15;
        #pragma unroll
        for (int kk = 0; kk < 4; ++kk) {
            bf16x8 af;
            #pragma unroll
            for (int ee = 0; ee < 8; ++ee)
                af[ee] = (short)f2b(W[(size_t)(kk * 32 + lg * 8 + ee) * 128 + col]);
            a[mt][kk] = af;
        }
    }

    #pragma unroll
    for (int p = 0; p < 4; ++p) {
        int idx = p * 256 + tid;
        int r = idx >> 4, ci = idx & 15;
        int row = tilebase + r;
        if (row >= N) row = N - 1;
        if (IN_F32) {
            const float* ip = (const float*)inp + (size_t)row * 128 + ci * 8;
            f32x4 x0 = *(const f32x4*)ip;
            f32x4 x1 = *(const f32x4*)(ip + 4);
            uint4 v;
            v.x = (unsigned int)f2b(x0[0]) | ((unsigned int)f2b(x0[1]) << 16);
            v.y = (unsigned int)f2b(x0[2]) | ((unsigned int)f2b(x0[3]) << 16);
            v.z = (unsigned int)f2b(x1[0]) | ((unsigned int)f2b(x1[1]) << 16);
            v.w = (unsigned int)f2b(x1[2]) | ((unsigned int)f2b(x1[3]) << 16);
            *(uint4*)&hl[r][ci * 8] = v;
        } else {
            *(uint4*)&hl[r][ci * 8] =
                *(const uint4*)((const unsigned short*)inp + (size_t)row * 128 + ci * 8);
        }
    }
    __syncthreads();

    f32x4 acc[2][4];
    #pragma unroll
    for (int mt = 0; mt < 2; ++mt)
        #pragma unroll
        for (int nt = 0; nt < 4; ++nt) acc[mt][nt] = (f32x4){0.f, 0.f, 0.f, 0.f};
    #pragma unroll
    for (int kk = 0; kk < 4; ++kk) {
        #pragma unroll
        for (int nt = 0; nt < 4; ++nt) {
            bf16x8 b = *(const bf16x8*)&hl[nt * 16 + l15][kk * 32 + lg * 8];
            acc[0][nt] = __builtin_amdgcn_mfma_f32_16x16x32_bf16(a[0][kk], b, acc[0][nt], 0, 0, 0);
            acc[1][nt] = __builtin_amdgcn_mfma_f32_16x16x32_bf16(a[1][kk], b, acc[1][nt], 0, 0, 0);
        }
    }
    #pragma unroll
    for (int mt = 0; mt < 2; ++mt) {
        int j = wid * 32 + mt * 16 + lg * 4;
        #pragma unroll
        for (int nt = 0; nt < 4; ++nt) {
            int node = tilebase + nt * 16 + l15;
            if (node < N) {
                unsigned int u0 = (unsigned int)f2b(acc[mt][nt][0]) | ((unsigned int)f2b(acc[mt][nt][1]) << 16);
                unsigned int u1 = (unsigned int)f2b(acc[mt][nt][2]) | ((unsigned int)f2b(acc[mt][nt][3]) << 16);
                *(uint2*)(outb + (size_t)node * 128 + j) = make_uint2(u0, u1);
            }
        }
    }
}

// ---------------- GCN aggregation: bf16 gather, 4-edge unroll, fp32 math ----------------

template <int RELU>
__global__ __launch_bounds__(256) void aggregate(
        const unsigned short* __restrict__ tb, const int* __restrict__ rowstart,
        const int* __restrict__ csr_src, const float* __restrict__ dinv,
        const float* __restrict__ bias, unsigned short* __restrict__ hb, int N) {
    int tid = threadIdx.x;
    int node = blockIdx.x * 8 + (tid >> 5);
    if (node >= N) return;
    int c = (tid & 31) * 4;
    float di = dinv[node];
    f32x4 self = b2f4(*(const ushort4*)(tb + (size_t)node * 128 + c));
    f32x4 acc = *(const f32x4*)(bias + c) + (di * di) * self;
    int rs = rowstart[node], re = rowstart[node + 1];
    int e = rs;
    for (; e + 3 < re; e += 4) {
        int s0 = csr_src[e], s1 = csr_src[e + 1];
        int s2 = csr_src[e + 2], s3 = csr_src[e + 3];
        float n0 = dinv[s0], n1 = dinv[s1], n2 = dinv[s2], n3 = dinv[s3];
        ushort4 r0 = *(const ushort4*)(tb + (size_t)s0 * 128 + c);
        ushort4 r1 = *(const ushort4*)(tb + (size_t)s1 * 128 + c);
        ushort4 r2 = *(const ushort4*)(tb + (size_t)s2 * 128 + c);
        ushort4 r3 = *(const ushort4*)(tb + (size_t)s3 * 128 + c);
        acc += (n0 * di) * b2f4(r0);
        acc += (n1 * di) * b2f4(r1);
        acc += (n2 * di) * b2f4(r2);
        acc += (n3 * di) * b2f4(r3);
    }
    for (; e < re; ++e) {
        int s0 = csr_src[e];
        acc += (dinv[s0] * di) * b2f4(*(const ushort4*)(tb + (size_t)s0 * 128 + c));
    }
    if (RELU) {
        #pragma unroll
        for (int j = 0; j < 4; ++j) acc[j] = fmaxf(acc[j], 0.f);
    }
    unsigned int u0 = (unsigned int)f2b(acc[0]) | ((unsigned int)f2b(acc[1]) << 16);
    unsigned int u1 = (unsigned int)f2b(acc[2]) | ((unsigned int)f2b(acc[3]) << 16);
    *(uint2*)(hb + (size_t)node * 128 + c) = make_uint2(u0, u1);
}

// ---------------- uv precompute: bf16 out ----------------

__global__ __launch_bounds__(256) void uv_gemm(const unsigned short* __restrict__ h3b,
                                               const float* __restrict__ Wm1,
                                               unsigned short* __restrict__ uvb, int N) {
    __shared__ __align__(16) unsigned short hl[64][136];
    int tid = threadIdx.x;
    int wid = tid >> 6, lane = tid & 63;
    int lg = lane >> 4, l15 = lane & 15;
    int tilebase = blockIdx.x * 64;

    bf16x8 a[4][4];
    #pragma unroll
    for (int mt = 0; mt < 4; ++mt) {
        int jc = wid * 64 + mt * 16 + l15;
        int koff = (jc >> 7) * 128;
        int col = jc & 127;
        #pragma unroll
        for (int kk = 0; kk < 4; ++kk) {
            bf16x8 af;
            #pragma unroll
            for (int ee = 0; ee < 8; ++ee)
                af[ee] = (short)f2b(Wm1[(size_t)(koff + kk * 32 + lg * 8 + ee) * 128 + col]);
            a[mt][kk] = af;
        }
    }

    #pragma unroll
    for (int p = 0; p < 4; ++p) {
        int idx = p * 256 + tid;
        int r = idx >> 4, ci = idx & 15;
        int row = tilebase + r;
        if (row >= N) row = N - 1;
        uint4 v = *(const uint4*)(h3b + (size_t)row * 128 + ci * 8);
        *(uint4*)&hl[r][ci * 8] = v;
    }
    __syncthreads();

    f32x4 acc[4][4];
    #pragma unroll
    for (int mt = 0; mt < 4; ++mt)
        #pragma unroll
        for (int nt = 0; nt < 4; ++nt) acc[mt][nt] = (f32x4){0.f, 0.f, 0.f, 0.f};
    #pragma unroll
    for (int kk = 0; kk < 4; ++kk) {
        #pragma unroll
        for (int nt = 0; nt < 4; ++nt) {
            bf16x8 b = *(const bf16x8*)&hl[nt * 16 + l15][kk * 32 + lg * 8];
            #pragma unroll
            for (int mt = 0; mt < 4; ++mt)
                acc[mt][nt] = __builtin_amdgcn_mfma_f32_16x16x32_bf16(a[mt][kk], b, acc[mt][nt], 0, 0, 0);
        }
    }
    #pragma unroll
    for (int mt = 0; mt < 4; ++mt) {
        int jc = wid * 64 + mt * 16 + lg * 4;
        #pragma unroll
        for (int nt = 0; nt < 4; ++nt) {
            int node = tilebase + nt * 16 + l15;
            if (node < N) {
                unsigned int u0 = (unsigned int)f2b(acc[mt][nt][0]) | ((unsigned int)f2b(acc[mt][nt][1]) << 16);
                unsigned int u1 = (unsigned int)f2b(acc[mt][nt][2]) | ((unsigned int)f2b(acc[mt][nt][3]) << 16);
                *(uint2*)(uvb + (size_t)node * 256 + jc) = make_uint2(u0, u1);
            }
        }
    }
}

// ---------------- edge head (CSR order): z = relu(u[src]+v[dst]+bm1); out[eid] = z@Wm2+bm2 ----

__global__ __launch_bounds__(256, 4) void edge_head3(
        const unsigned short* __restrict__ uvb, const int* __restrict__ csr_src,
        const int* __restrict__ csr_dst, const int* __restrict__ csr_eid,
        const float* __restrict__ bm1, const float* __restrict__ Wm2,
        const float* __restrict__ bm2, float* __restrict__ out, int E, int ntiles) {
    __shared__ __align__(16) unsigned short zl[64][136];
    __shared__ int eid_l[64];
    int tid = threadIdx.x;
    int wid = tid >> 6, lane = tid & 63;
    int lg = lane >> 4, l15 = lane & 15;
    int es = tid >> 4;
    int ci = tid & 15;
    int c0 = ci * 8;

    bf16x8 a2[2][4];
    float b2v[2][4];
    #pragma unroll
    for (int mt = 0; mt < 2; ++mt) {
        int m = wid * 32 + mt * 16 + l15;
        #pragma unroll
        for (int kk = 0; kk < 4; ++kk) {
            bf16x8 af;
            #pragma unroll
            for (int ee = 0; ee < 8; ++ee)
                af[ee] = (short)f2b(Wm2[(size_t)(kk * 32 + lg * 8 + ee) * 128 + m]);
            a2[mt][kk] = af;
        }
        #pragma unroll
        for (int r = 0; r < 4; ++r)
            b2v[mt][r] = bm2[wid * 32 + mt * 16 + lg * 4 + r];
    }
    float bm1v[8];
    #pragma unroll
    for (int j = 0; j < 8; ++j) bm1v[j] = bm1[c0 + j];

    for (int tile = blockIdx.x; tile < ntiles; tile += gridDim.x) {
        __syncthreads();
        #pragma unroll
        for (int p = 0; p < 4; ++p) {
            int slot = tile * 64 + p * 16 + es;
            int cs = (slot < E) ? slot : (E - 1);
            int s = csr_src[cs], d = csr_dst[cs];
            if (ci == 0) eid_l[p * 16 + es] = (slot < E) ? csr_eid[cs] : -1;
            uint4 uu = *(const uint4*)(uvb + (size_t)s * 256 + c0);
            uint4 vv = *(const uint4*)(uvb + (size_t)d * 256 + 128 + c0);
            unsigned int w[4];
            {
                float z0 = fmaxf(b2f((unsigned short)(uu.x)) + b2f((unsigned short)(vv.x)) + bm1v[0], 0.f);
                float z1 = fmaxf(b2f((unsigned short)(uu.x >> 16)) + b2f((unsigned short)(vv.x >> 16)) + bm1v[1], 0.f);
                float z2 = fmaxf(b2f((unsigned short)(uu.y)) + b2f((unsigned short)(vv.y)) + bm1v[2], 0.f);
                float z3 = fmaxf(b2f((unsigned short)(uu.y >> 16)) + b2f((unsigned short)(vv.y >> 16)) + bm1v[3], 0.f);
                float z4 = fmaxf(b2f((unsigned short)(uu.z)) + b2f((unsigned short)(vv.z)) + bm1v[4], 0.f);
                float z5 = fmaxf(b2f((unsigned short)(uu.z >> 16)) + b2f((unsigned short)(vv.z >> 16)) + bm1v[5], 0.f);
                float z6 = fmaxf(b2f((unsigned short)(uu.w)) + b2f((unsigned short)(vv.w)) + bm1v[6], 0.f);
                float z7 = fmaxf(b2f((unsigned short)(uu.w >> 16)) + b2f((unsigned short)(vv.w >> 16)) + bm1v[7], 0.f);
                w[0] = (unsigned int)f2b(z0) | ((unsigned int)f2b(z1) << 16);
                w[1] = (unsigned int)f2b(z2) | ((unsigned int)f2b(z3) << 16);
                w[2] = (unsigned int)f2b(z4) | ((unsigned int)f2b(z5) << 16);
                w[3] = (unsigned int)f2b(z6) | ((unsigned int)f2b(z7) << 16);
            }
            *(uint4*)&zl[p * 16 + es][c0] = make_uint4(w[0], w[1], w[2], w[3]);
        }
        __syncthreads();

        f32x4 c2[2][4];
        #pragma unroll
        for (int mt = 0; mt < 2; ++mt)
            #pragma unroll
            for (int nt = 0; nt < 4; ++nt) c2[mt][nt] = (f32x4){0.f, 0.f, 0.f, 0.f};
        #pragma unroll
        for (int kk = 0; kk < 4; ++kk) {
            #pragma unroll
            for (int nt = 0; nt < 4; ++nt) {
                bf16x8 b = *(const bf16x8*)&zl[nt * 16 + l15][kk * 32 + lg * 8];
                c2[0][nt] = __builtin_amdgcn_mfma_f32_16x16x32_bf16(a2[0][kk], b, c2[0][nt], 0, 0, 0);
                c2[1][nt] = __builtin_amdgcn_mfma_f32_16x16x32_bf16(a2[1][kk], b, c2[1][nt], 0, 0, 0);
            }
        }
        #pragma unroll
        for (int mt = 0; mt < 2; ++mt) {
            #pragma unroll
            for (int nt = 0; nt < 4; ++nt) {
                int eg = eid_l[nt * 16 + l15];
                if (eg >= 0) {
                    f32x4 o;
                    #pragma unroll
                    for (int r = 0; r < 4; ++r) o[r] = c2[mt][nt][r] + b2v[mt][r];
                    *(f32x4*)(out + (size_t)eg * 128 + wid * 32 + mt * 16 + lg * 4) = o;
                }
            }
        }
    }
}

// ---------------- launch ----------------

extern "C" void kernel_launch(void* const* d_in, const int* in_sizes, int n_in,
                              void* d_out, int out_size, void* d_ws, size_t ws_size,
                              hipStream_t stream) {
    const float* x  = (const float*)d_in[0];
    const int*   ei = (const int*)d_in[1];
    const float* W1 = (const float*)d_in[2];
    const float* b1 = (const float*)d_in[3];
    const float* W2 = (const float*)d_in[4];
    const float* b2 = (const float*)d_in[5];
    const float* W3 = (const float*)d_in[6];
    const float* b3 = (const float*)d_in[7];
    const float* Wm1 = (const float*)d_in[8];
    const float* bm1 = (const float*)d_in[9];
    const float* Wm2 = (const float*)d_in[10];
    const float* bm2 = (const float*)d_in[11];
    float* out = (float*)d_out;

    const int N = in_sizes[0] / 128;
    const int E = in_sizes[1] / 2;
    const int* src = ei;
    const int* dstp = ei + E;

    uintptr_t base = (uintptr_t)d_ws;
    auto alloc = [&](size_t bytes) -> void* {
        uintptr_t p = base;
        base += (bytes + 255) & ~(uintptr_t)255;
        return (void*)p;
    };
    int*   counts   = (int*)alloc((size_t)(N + 1) * 4);
    int*   rowstart = (int*)alloc((size_t)(N + 1) * 4);
    int*   cursor   = (int*)alloc((size_t)N * 4);
    float* dinv     = (float*)alloc((size_t)N * 4);
    int*   psum     = (int*)alloc(4096);
    int*   csr_s    = (int*)alloc((size_t)E * 4);
    int*   csr_d    = (int*)alloc((size_t)E * 4);
    int*   csr_e    = (int*)alloc((size_t)E * 4);
    unsigned short* tb  = (unsigned short*)alloc((size_t)N * 128 * 2);
    unsigned short* hb  = (unsigned short*)alloc((size_t)N * 128 * 2);
    unsigned short* uvb = (unsigned short*)alloc((size_t)N * 256 * 2);
    (void)ws_size; (void)n_in; (void)out_size;

    hipMemsetAsync(counts, 0, (size_t)(N + 1) * 4, stream);

    int egrid = (E + 255) / 256;
    int nchunk = (N + 1023) / 1024;
    count_deg<<<egrid, 256, 0, stream>>>(dstp, E, counts);
    scan_s1<<<nchunk, 1024, 0, stream>>>(counts, N, rowstart, dinv, psum);
    scan_s2<<<1, 1024, 0, stream>>>(psum, nchunk, rowstart, N);
    scan_s3<<<nchunk, 1024, 0, stream>>>(rowstart, psum, N, cursor);
    fill_csr<<<egrid, 256, 0, stream>>>(src, dstp, E, cursor, csr_s, csr_d, csr_e);

    int ggrid = (N + 63) / 64;
    int agrid = (N + 7) / 8;
    node_mfma<1><<<ggrid, 256, 0, stream>>>(x, W1, tb, N);
    aggregate<1><<<agrid, 256, 0, stream>>>(tb, rowstart, csr_s, dinv, b1, hb, N);
    node_mfma<0><<<ggrid, 256, 0, stream>>>(hb, W2, tb, N);
    aggregate<1><<<agrid, 256, 0, stream>>>(tb, rowstart, csr_s, dinv, b2, hb, N);
    node_mfma<0><<<ggrid, 256, 0, stream>>>(hb, W3, tb, N);
    aggregate<0><<<agrid, 256, 0, stream>>>(tb, rowstart, csr_s, dinv, b3, hb, N);

    uv_gemm<<<ggrid, 256, 0, stream>>>(hb, Wm1, uvb, N);

    int ntiles = (E + 63) / 64;
    int hgrid = ntiles < 2048 ? ntiles : 2048;
    edge_head3<<<hgrid, 256, 0, stream>>>(uvb, csr_s, csr_d, csr_e, bm1, Wm2, bm2, out, E, ntiles);
}

// Round 6
// 427.381 us; speedup vs baseline: 1.5245x; 1.0090x over previous
//
#include <hip/hip_runtime.h>
#include <stdint.h>

typedef __attribute__((ext_vector_type(8))) short bf16x8;
typedef __attribute__((ext_vector_type(4))) float f32x4;

static __device__ __forceinline__ unsigned short f2b(float f) {
    unsigned int u = __float_as_uint(f);
    unsigned int r = u + 0x7fffu + ((u >> 16) & 1u);   // RNE
    return (unsigned short)(r >> 16);
}
static __device__ __forceinline__ float b2f(unsigned short u) {
    return __uint_as_float((unsigned int)u << 16);
}
static __device__ __forceinline__ f32x4 b2f4(ushort4 u) {
    f32x4 r;
    r[0] = b2f(u.x); r[1] = b2f(u.y); r[2] = b2f(u.z); r[3] = b2f(u.w);
    return r;
}

// ---------------- CSR build ----------------

__global__ void count_deg(const int* __restrict__ dst, int E, int* __restrict__ counts) {
    int e = blockIdx.x * 256 + threadIdx.x;
    if (e < E) atomicAdd(&counts[dst[e]], 1);
}

__global__ void scan_s1(const int* __restrict__ counts, int N,
                        int* __restrict__ rowstart, float* __restrict__ dinv,
                        int* __restrict__ psum) {
    __shared__ int wsum[16];
    int tid = threadIdx.x, wave = tid >> 6, lane = tid & 63;
    int i = blockIdx.x * 1024 + tid;
    int c = (i < N) ? counts[i] : 0;
    int x = c;
    #pragma unroll
    for (int off = 1; off < 64; off <<= 1) {
        int v = __shfl_up(x, off);
        if (lane >= off) x += v;
    }
    if (lane == 63) wsum[wave] = x;
    __syncthreads();
    int pre = 0, tot = 0;
    #pragma unroll
    for (int w = 0; w < 16; ++w) {
        int s = wsum[w];
        tot += s;
        if (w < wave) pre += s;
    }
    if (i < N) {
        rowstart[i] = pre + x - c;
        dinv[i] = rsqrtf((float)c + 1.0f);
    }
    if (tid == 0) psum[blockIdx.x] = tot;
}

__global__ void scan_s2(int* __restrict__ psum, int nchunk,
                        int* __restrict__ rowstart, int N) {
    __shared__ int wsum[16];
    int tid = threadIdx.x, wave = tid >> 6, lane = tid & 63;
    int v = (tid < nchunk) ? psum[tid] : 0;
    int x = v;
    #pragma unroll
    for (int off = 1; off < 64; off <<= 1) {
        int s = __shfl_up(x, off);
        if (lane >= off) x += s;
    }
    if (lane == 63) wsum[wave] = x;
    __syncthreads();
    int pre = 0, tot = 0;
    #pragma unroll
    for (int w = 0; w < 16; ++w) {
        int s = wsum[w];
        tot += s;
        if (w < wave) pre += s;
    }
    if (tid < nchunk) psum[tid] = pre + x - v;
    if (tid == 0) rowstart[N] = tot;
}

__global__ void scan_s3(int* __restrict__ rowstart, const int* __restrict__ psum,
                        int N, int* __restrict__ cursor) {
    int i = blockIdx.x * 1024 + threadIdx.x;
    if (i < N) {
        int r = rowstart[i] + psum[blockIdx.x];
        rowstart[i] = r;
        cursor[i] = r;
    }
}

// packs (src, norm=dinv[src]*dinv[dst]) per CSR slot
__global__ void fill_csr(const int* __restrict__ src, const int* __restrict__ dst, int E,
                         int* __restrict__ cursor, const float* __restrict__ dinv,
                         int2* __restrict__ csr_sn, int* __restrict__ csr_dst,
                         int* __restrict__ csr_eid) {
    int e = blockIdx.x * 256 + threadIdx.x;
    if (e < E) {
        int d = dst[e], s = src[e];
        int p = atomicAdd(&cursor[d], 1);
        float nrm = dinv[s] * dinv[d];
        csr_sn[p] = make_int2(s, __float_as_int(nrm));
        csr_dst[p] = d;
        csr_eid[p] = e;
    }
}

// ---------------- node GEMM via MFMA: t = bf16(in) @ bf16(W), fp32 accum, bf16 out ----

template <int IN_F32>
__global__ __launch_bounds__(256) void node_mfma(const void* __restrict__ inp,
                                                 const float* __restrict__ W,
                                                 unsigned short* __restrict__ outb, int N) {
    __shared__ __align__(16) unsigned short hl[64][136];
    int tid = threadIdx.x;
    int wid = tid >> 6, lane = tid & 63;
    int lg = lane >> 4, l15 = lane & 15;
    int tilebase = blockIdx.x * 64;

    bf16x8 a[2][4];
    #pragma unroll
    for (int mt = 0; mt < 2; ++mt) {
        int col = wid * 32 + mt * 16 + l15;
        #pragma unroll
        for (int kk = 0; kk < 4; ++kk) {
            bf16x8 af;
            #pragma unroll
            for (int ee = 0; ee < 8; ++ee)
                af[ee] = (short)f2b(W[(size_t)(kk * 32 + lg * 8 + ee) * 128 + col]);
            a[mt][kk] = af;
        }
    }

    #pragma unroll
    for (int p = 0; p < 4; ++p) {
        int idx = p * 256 + tid;
        int r = idx >> 4, ci = idx & 15;
        int row = tilebase + r;
        if (row >= N) row = N - 1;
        if (IN_F32) {
            const float* ip = (const float*)inp + (size_t)row * 128 + ci * 8;
            f32x4 x0 = *(const f32x4*)ip;
            f32x4 x1 = *(const f32x4*)(ip + 4);
            uint4 v;
            v.x = (unsigned int)f2b(x0[0]) | ((unsigned int)f2b(x0[1]) << 16);
            v.y = (unsigned int)f2b(x0[2]) | ((unsigned int)f2b(x0[3]) << 16);
            v.z = (unsigned int)f2b(x1[0]) | ((unsigned int)f2b(x1[1]) << 16);
            v.w = (unsigned int)f2b(x1[2]) | ((unsigned int)f2b(x1[3]) << 16);
            *(uint4*)&hl[r][ci * 8] = v;
        } else {
            *(uint4*)&hl[r][ci * 8] =
                *(const uint4*)((const unsigned short*)inp + (size_t)row * 128 + ci * 8);
        }
    }
    __syncthreads();

    f32x4 acc[2][4];
    #pragma unroll
    for (int mt = 0; mt < 2; ++mt)
        #pragma unroll
        for (int nt = 0; nt < 4; ++nt) acc[mt][nt] = (f32x4){0.f, 0.f, 0.f, 0.f};
    #pragma unroll
    for (int kk = 0; kk < 4; ++kk) {
        #pragma unroll
        for (int nt = 0; nt < 4; ++nt) {
            bf16x8 b = *(const bf16x8*)&hl[nt * 16 + l15][kk * 32 + lg * 8];
            acc[0][nt] = __builtin_amdgcn_mfma_f32_16x16x32_bf16(a[0][kk], b, acc[0][nt], 0, 0, 0);
            acc[1][nt] = __builtin_amdgcn_mfma_f32_16x16x32_bf16(a[1][kk], b, acc[1][nt], 0, 0, 0);
        }
    }
    #pragma unroll
    for (int mt = 0; mt < 2; ++mt) {
        int j = wid * 32 + mt * 16 + lg * 4;
        #pragma unroll
        for (int nt = 0; nt < 4; ++nt) {
            int node = tilebase + nt * 16 + l15;
            if (node < N) {
                unsigned int u0 = (unsigned int)f2b(acc[mt][nt][0]) | ((unsigned int)f2b(acc[mt][nt][1]) << 16);
                unsigned int u1 = (unsigned int)f2b(acc[mt][nt][2]) | ((unsigned int)f2b(acc[mt][nt][3]) << 16);
                *(uint2*)(outb + (size_t)node * 128 + j) = make_uint2(u0, u1);
            }
        }
    }
}

// ---------------- GCN aggregation: packed (src,norm), 8-row batches ----------------

template <int RELU>
__global__ __launch_bounds__(256) void aggregate(
        const unsigned short* __restrict__ tb, const int* __restrict__ rowstart,
        const int2* __restrict__ csr_sn, const float* __restrict__ dinv,
        const float* __restrict__ bias, unsigned short* __restrict__ hb, int N) {
    int tid = threadIdx.x;
    int node = blockIdx.x * 8 + (tid >> 5);
    if (node >= N) return;
    int c = (tid & 31) * 4;
    float di = dinv[node];
    f32x4 self = b2f4(*(const ushort4*)(tb + (size_t)node * 128 + c));
    f32x4 acc = *(const f32x4*)(bias + c) + (di * di) * self;
    int e = rowstart[node], re = rowstart[node + 1];
    for (; e + 7 < re; e += 8) {
        int2 p0 = csr_sn[e + 0], p1 = csr_sn[e + 1], p2 = csr_sn[e + 2], p3 = csr_sn[e + 3];
        int2 p4 = csr_sn[e + 4], p5 = csr_sn[e + 5], p6 = csr_sn[e + 6], p7 = csr_sn[e + 7];
        ushort4 r0 = *(const ushort4*)(tb + (size_t)p0.x * 128 + c);
        ushort4 r1 = *(const ushort4*)(tb + (size_t)p1.x * 128 + c);
        ushort4 r2 = *(const ushort4*)(tb + (size_t)p2.x * 128 + c);
        ushort4 r3 = *(const ushort4*)(tb + (size_t)p3.x * 128 + c);
        ushort4 r4 = *(const ushort4*)(tb + (size_t)p4.x * 128 + c);
        ushort4 r5 = *(const ushort4*)(tb + (size_t)p5.x * 128 + c);
        ushort4 r6 = *(const ushort4*)(tb + (size_t)p6.x * 128 + c);
        ushort4 r7 = *(const ushort4*)(tb + (size_t)p7.x * 128 + c);
        acc += __int_as_float(p0.y) * b2f4(r0);
        acc += __int_as_float(p1.y) * b2f4(r1);
        acc += __int_as_float(p2.y) * b2f4(r2);
        acc += __int_as_float(p3.y) * b2f4(r3);
        acc += __int_as_float(p4.y) * b2f4(r4);
        acc += __int_as_float(p5.y) * b2f4(r5);
        acc += __int_as_float(p6.y) * b2f4(r6);
        acc += __int_as_float(p7.y) * b2f4(r7);
    }
    for (; e + 3 < re; e += 4) {
        int2 p0 = csr_sn[e + 0], p1 = csr_sn[e + 1], p2 = csr_sn[e + 2], p3 = csr_sn[e + 3];
        ushort4 r0 = *(const ushort4*)(tb + (size_t)p0.x * 128 + c);
        ushort4 r1 = *(const ushort4*)(tb + (size_t)p1.x * 128 + c);
        ushort4 r2 = *(const ushort4*)(tb + (size_t)p2.x * 128 + c);
        ushort4 r3 = *(const ushort4*)(tb + (size_t)p3.x * 128 + c);
        acc += __int_as_float(p0.y) * b2f4(r0);
        acc += __int_as_float(p1.y) * b2f4(r1);
        acc += __int_as_float(p2.y) * b2f4(r2);
        acc += __int_as_float(p3.y) * b2f4(r3);
    }
    for (; e < re; ++e) {
        int2 p0 = csr_sn[e];
        acc += __int_as_float(p0.y) * b2f4(*(const ushort4*)(tb + (size_t)p0.x * 128 + c));
    }
    if (RELU) {
        #pragma unroll
        for (int j = 0; j < 4; ++j) acc[j] = fmaxf(acc[j], 0.f);
    }
    unsigned int u0 = (unsigned int)f2b(acc[0]) | ((unsigned int)f2b(acc[1]) << 16);
    unsigned int u1 = (unsigned int)f2b(acc[2]) | ((unsigned int)f2b(acc[3]) << 16);
    *(uint2*)(hb + (size_t)node * 128 + c) = make_uint2(u0, u1);
}

// ---------------- uv precompute: bf16 out ----------------

__global__ __launch_bounds__(256) void uv_gemm(const unsigned short* __restrict__ h3b,
                                               const float* __restrict__ Wm1,
                                               unsigned short* __restrict__ uvb, int N) {
    __shared__ __align__(16) unsigned short hl[64][136];
    int tid = threadIdx.x;
    int wid = tid >> 6, lane = tid & 63;
    int lg = lane >> 4, l15 = lane & 15;
    int tilebase = blockIdx.x * 64;

    bf16x8 a[4][4];
    #pragma unroll
    for (int mt = 0; mt < 4; ++mt) {
        int jc = wid * 64 + mt * 16 + l15;
        int koff = (jc >> 7) * 128;
        int col = jc & 127;
        #pragma unroll
        for (int kk = 0; kk < 4; ++kk) {
            bf16x8 af;
            #pragma unroll
            for (int ee = 0; ee < 8; ++ee)
                af[ee] = (short)f2b(Wm1[(size_t)(koff + kk * 32 + lg * 8 + ee) * 128 + col]);
            a[mt][kk] = af;
        }
    }

    #pragma unroll
    for (int p = 0; p < 4; ++p) {
        int idx = p * 256 + tid;
        int r = idx >> 4, ci = idx & 15;
        int row = tilebase + r;
        if (row >= N) row = N - 1;
        uint4 v = *(const uint4*)(h3b + (size_t)row * 128 + ci * 8);
        *(uint4*)&hl[r][ci * 8] = v;
    }
    __syncthreads();

    f32x4 acc[4][4];
    #pragma unroll
    for (int mt = 0; mt < 4; ++mt)
        #pragma unroll
        for (int nt = 0; nt < 4; ++nt) acc[mt][nt] = (f32x4){0.f, 0.f, 0.f, 0.f};
    #pragma unroll
    for (int kk = 0; kk < 4; ++kk) {
        #pragma unroll
        for (int nt = 0; nt < 4; ++nt) {
            bf16x8 b = *(const bf16x8*)&hl[nt * 16 + l15][kk * 32 + lg * 8];
            #pragma unroll
            for (int mt = 0; mt < 4; ++mt)
                acc[mt][nt] = __builtin_amdgcn_mfma_f32_16x16x32_bf16(a[mt][kk], b, acc[mt][nt], 0, 0, 0);
        }
    }
    #pragma unroll
    for (int mt = 0; mt < 4; ++mt) {
        int jc = wid * 64 + mt * 16 + lg * 4;
        #pragma unroll
        for (int nt = 0; nt < 4; ++nt) {
            int node = tilebase + nt * 16 + l15;
            if (node < N) {
                unsigned int u0 = (unsigned int)f2b(acc[mt][nt][0]) | ((unsigned int)f2b(acc[mt][nt][1]) << 16);
                unsigned int u1 = (unsigned int)f2b(acc[mt][nt][2]) | ((unsigned int)f2b(acc[mt][nt][3]) << 16);
                *(uint2*)(uvb + (size_t)node * 256 + jc) = make_uint2(u0, u1);
            }
        }
    }
}

// ---------------- edge head (CSR order, pipelined): z = relu(u[src]+v[dst]+bm1); out[eid] = z@Wm2+bm2 ----

__global__ __launch_bounds__(256, 3) void edge_head4(
        const unsigned short* __restrict__ uvb, const int2* __restrict__ csr_sn,
        const int* __restrict__ csr_dst, const int* __restrict__ csr_eid,
        const float* __restrict__ bm1, const float* __restrict__ Wm2,
        const float* __restrict__ bm2, float* __restrict__ out, int E, int ntiles) {
    __shared__ __align__(16) unsigned short zl[64][136];
    __shared__ int eid_l[64];
    int tid = threadIdx.x;
    int wid = tid >> 6, lane = tid & 63;
    int lg = lane >> 4, l15 = lane & 15;
    int es = tid >> 4;
    int ci = tid & 15;
    int c0 = ci * 8;

    bf16x8 a2[2][4];
    float b2v[2][4];
    #pragma unroll
    for (int mt = 0; mt < 2; ++mt) {
        int m = wid * 32 + mt * 16 + l15;
        #pragma unroll
        for (int kk = 0; kk < 4; ++kk) {
            bf16x8 af;
            #pragma unroll
            for (int ee = 0; ee < 8; ++ee)
                af[ee] = (short)f2b(Wm2[(size_t)(kk * 32 + lg * 8 + ee) * 128 + m]);
            a2[mt][kk] = af;
        }
        #pragma unroll
        for (int r = 0; r < 4; ++r)
            b2v[mt][r] = bm2[wid * 32 + mt * 16 + lg * 4 + r];
    }
    float bm1v[8];
    #pragma unroll
    for (int j = 0; j < 8; ++j) bm1v[j] = bm1[c0 + j];

    uint4 uuA[4], uuB[4];
    int dA[4], dB[4], eidA[4], eidB[4];

    auto stage = [&](int tile, uint4 (&uu)[4], int (&dd)[4], int (&ee)[4]) {
        #pragma unroll
        for (int p = 0; p < 4; ++p) {
            int slot = tile * 64 + p * 16 + es;
            int cs = (slot < E) ? slot : (E - 1);
            int s = csr_sn[cs].x;
            dd[p] = csr_dst[cs];
            ee[p] = (slot < E) ? csr_eid[cs] : -1;
            uu[p] = *(const uint4*)(uvb + (size_t)s * 256 + c0);
        }
    };

    int t = blockIdx.x;
    if (t < ntiles) stage(t, uuA, dA, eidA);
    for (; t < ntiles; t += gridDim.x) {
        __syncthreads();   // zl free (previous MFMA done)
        // ---- consume A: v-gather (run-local) + z pack ----
        #pragma unroll
        for (int p = 0; p < 4; ++p) {
            uint4 vv = *(const uint4*)(uvb + (size_t)dA[p] * 256 + 128 + c0);
            uint4 uu = uuA[p];
            float z0 = fmaxf(b2f((unsigned short)(uu.x)) + b2f((unsigned short)(vv.x)) + bm1v[0], 0.f);
            float z1 = fmaxf(b2f((unsigned short)(uu.x >> 16)) + b2f((unsigned short)(vv.x >> 16)) + bm1v[1], 0.f);
            float z2 = fmaxf(b2f((unsigned short)(uu.y)) + b2f((unsigned short)(vv.y)) + bm1v[2], 0.f);
            float z3 = fmaxf(b2f((unsigned short)(uu.y >> 16)) + b2f((unsigned short)(vv.y >> 16)) + bm1v[3], 0.f);
            float z4 = fmaxf(b2f((unsigned short)(uu.z)) + b2f((unsigned short)(vv.z)) + bm1v[4], 0.f);
            float z5 = fmaxf(b2f((unsigned short)(uu.z >> 16)) + b2f((unsigned short)(vv.z >> 16)) + bm1v[5], 0.f);
            float z6 = fmaxf(b2f((unsigned short)(uu.w)) + b2f((unsigned short)(vv.w)) + bm1v[6], 0.f);
            float z7 = fmaxf(b2f((unsigned short)(uu.w >> 16)) + b2f((unsigned short)(vv.w >> 16)) + bm1v[7], 0.f);
            uint4 w;
            w.x = (unsigned int)f2b(z0) | ((unsigned int)f2b(z1) << 16);
            w.y = (unsigned int)f2b(z2) | ((unsigned int)f2b(z3) << 16);
            w.z = (unsigned int)f2b(z4) | ((unsigned int)f2b(z5) << 16);
            w.w = (unsigned int)f2b(z6) | ((unsigned int)f2b(z7) << 16);
            *(uint4*)&zl[p * 16 + es][c0] = w;
            if (ci == 0) eid_l[p * 16 + es] = eidA[p];
        }
        // ---- prefetch next tile's u rows (latency hidden under MFMA+stores) ----
        int tn = t + gridDim.x;
        bool more = (tn < ntiles);
        if (more) stage(tn, uuB, dB, eidB);
        __syncthreads();   // zl ready

        // ---- GEMM2 + store ----
        f32x4 c2[2][4];
        #pragma unroll
        for (int mt = 0; mt < 2; ++mt)
            #pragma unroll
            for (int nt = 0; nt < 4; ++nt) c2[mt][nt] = (f32x4){0.f, 0.f, 0.f, 0.f};
        #pragma unroll
        for (int kk = 0; kk < 4; ++kk) {
            #pragma unroll
            for (int nt = 0; nt < 4; ++nt) {
                bf16x8 b = *(const bf16x8*)&zl[nt * 16 + l15][kk * 32 + lg * 8];
                c2[0][nt] = __builtin_amdgcn_mfma_f32_16x16x32_bf16(a2[0][kk], b, c2[0][nt], 0, 0, 0);
                c2[1][nt] = __builtin_amdgcn_mfma_f32_16x16x32_bf16(a2[1][kk], b, c2[1][nt], 0, 0, 0);
            }
        }
        #pragma unroll
        for (int mt = 0; mt < 2; ++mt) {
            #pragma unroll
            for (int nt = 0; nt < 4; ++nt) {
                int eg = eid_l[nt * 16 + l15];
                if (eg >= 0) {
                    f32x4 o;
                    #pragma unroll
                    for (int r = 0; r < 4; ++r) o[r] = c2[mt][nt][r] + b2v[mt][r];
                    *(f32x4*)(out + (size_t)eg * 128 + wid * 32 + mt * 16 + lg * 4) = o;
                }
            }
        }
        if (more) {
            #pragma unroll
            for (int p = 0; p < 4; ++p) {
                uuA[p] = uuB[p]; dA[p] = dB[p]; eidA[p] = eidB[p];
            }
        }
    }
}

// ---------------- launch ----------------

extern "C" void kernel_launch(void* const* d_in, const int* in_sizes, int n_in,
                              void* d_out, int out_size, void* d_ws, size_t ws_size,
                              hipStream_t stream) {
    const float* x  = (const float*)d_in[0];
    const int*   ei = (const int*)d_in[1];
    const float* W1 = (const float*)d_in[2];
    const float* b1 = (const float*)d_in[3];
    const float* W2 = (const float*)d_in[4];
    const float* b2 = (const float*)d_in[5];
    const float* W3 = (const float*)d_in[6];
    const float* b3 = (const float*)d_in[7];
    const float* Wm1 = (const float*)d_in[8];
    const float* bm1 = (const float*)d_in[9];
    const float* Wm2 = (const float*)d_in[10];
    const float* bm2 = (const float*)d_in[11];
    float* out = (float*)d_out;

    const int N = in_sizes[0] / 128;
    const int E = in_sizes[1] / 2;
    const int* src = ei;
    const int* dstp = ei + E;

    uintptr_t base = (uintptr_t)d_ws;
    auto alloc = [&](size_t bytes) -> void* {
        uintptr_t p = base;
        base += (bytes + 255) & ~(uintptr_t)255;
        return (void*)p;
    };
    int*   counts   = (int*)alloc((size_t)(N + 1) * 4);
    int*   rowstart = (int*)alloc((size_t)(N + 1) * 4);
    int*   cursor   = (int*)alloc((size_t)N * 4);
    float* dinv     = (float*)alloc((size_t)N * 4);
    int*   psum     = (int*)alloc(4096);
    int2*  csr_sn   = (int2*)alloc((size_t)E * 8);
    int*   csr_d    = (int*)alloc((size_t)E * 4);
    int*   csr_e    = (int*)alloc((size_t)E * 4);
    unsigned short* tb  = (unsigned short*)alloc((size_t)N * 128 * 2);
    unsigned short* hb  = (unsigned short*)alloc((size_t)N * 128 * 2);
    unsigned short* uvb = (unsigned short*)alloc((size_t)N * 256 * 2);
    (void)ws_size; (void)n_in; (void)out_size;

    hipMemsetAsync(counts, 0, (size_t)(N + 1) * 4, stream);

    int egrid = (E + 255) / 256;
    int nchunk = (N + 1023) / 1024;
    count_deg<<<egrid, 256, 0, stream>>>(dstp, E, counts);
    scan_s1<<<nchunk, 1024, 0, stream>>>(counts, N, rowstart, dinv, psum);
    scan_s2<<<1, 1024, 0, stream>>>(psum, nchunk, rowstart, N);
    scan_s3<<<nchunk, 1024, 0, stream>>>(rowstart, psum, N, cursor);
    fill_csr<<<egrid, 256, 0, stream>>>(src, dstp, E, cursor, dinv, csr_sn, csr_d, csr_e);

    int ggrid = (N + 63) / 64;
    int agrid = (N + 7) / 8;
    node_mfma<1><<<ggrid, 256, 0, stream>>>(x, W1, tb, N);
    aggregate<1><<<agrid, 256, 0, stream>>>(tb, rowstart, csr_sn, dinv, b1, hb, N);
    node_mfma<0><<<ggrid, 256, 0, stream>>>(hb, W2, tb, N);
    aggregate<1><<<agrid, 256, 0, stream>>>(tb, rowstart, csr_sn, dinv, b2, hb, N);
    node_mfma<0><<<ggrid, 256, 0, stream>>>(hb, W3, tb, N);
    aggregate<0><<<agrid, 256, 0, stream>>>(tb, rowstart, csr_sn, dinv, b3, hb, N);

    uv_gemm<<<ggrid, 256, 0, stream>>>(hb, Wm1, uvb, N);

    int ntiles = (E + 63) / 64;
    int hgrid = ntiles < 768 ? ntiles : 768;
    edge_head4<<<hgrid, 256, 0, stream>>>(uvb, csr_sn, csr_d, csr_e, bm1, Wm2, bm2, out, E, ntiles);
}